// Round 1
// baseline (3473.767 us; speedup 1.0000x reference)
//
#include <hip/hip_runtime.h>

#define N_NODES  50000
#define N_EDGES  800000
#define E_TOT    850000   // edges + self loops
#define N_GRAPHS 64
#define NHID     64
#define NHEADS   4
#define HW       256      // NHEADS*NHID
#define NEG_SLOPE 0.2f

// ---------------- encoder: Y = X = [x|pos] @ enc_w + enc_b ----------------
__global__ void encoder_kernel(const float* __restrict__ x, const float* __restrict__ pos,
                               const float* __restrict__ enc_w, const float* __restrict__ enc_b,
                               float* __restrict__ Y, float* __restrict__ X) {
    int n = blockIdx.x;
    int c = threadIdx.x;            // 0..63
    __shared__ float row[128];
    for (int k = c; k < 128; k += 64)
        row[k] = (k < 125) ? x[n * 125 + k] : pos[n * 3 + (k - 125)];
    __syncthreads();
    float acc = enc_b[c];
    #pragma unroll 8
    for (int k = 0; k < 128; ++k) acc += row[k] * enc_w[k * 64 + c];
    Y[n * 64 + c] = acc;
    X[n * 64 + c] = acc;
}

// ---------------- h = X @ lin_w ; a_src/a_dst per head ----------------
__global__ void lin_kernel(const float* __restrict__ X, const float* __restrict__ lin_w,
                           const float* __restrict__ att_src, const float* __restrict__ att_dst,
                           float* __restrict__ h, float* __restrict__ a_src, float* __restrict__ a_dst) {
    int n = blockIdx.x;
    int t = threadIdx.x;            // 0..255
    __shared__ float xrow[64];
    if (t < 64) xrow[t] = X[n * 64 + t];
    __syncthreads();
    float acc = 0.f;
    #pragma unroll 8
    for (int k = 0; k < 64; ++k) acc += xrow[k] * lin_w[k * 256 + t];
    h[n * 256 + t] = acc;
    int head = t >> 6, c = t & 63;  // each wave (64 lanes) == one head
    float ps = acc * att_src[head * 64 + c];
    float pd = acc * att_dst[head * 64 + c];
    for (int off = 32; off >= 1; off >>= 1) {
        ps += __shfl_down(ps, off);
        pd += __shfl_down(pd, off);
    }
    if (c == 0) { a_src[n * 4 + head] = ps; a_dst[n * 4 + head] = pd; }
}

// ---------------- per-layer init: conv=0, m=-inf, z=0 ----------------
__global__ void layer_init_kernel(float* __restrict__ conv, float* __restrict__ m,
                                  float* __restrict__ z) {
    int i = blockIdx.x * blockDim.x + threadIdx.x;
    if (i < N_NODES * HW) conv[i] = 0.f;
    if (i < N_NODES * NHEADS) { m[i] = -3.0e38f; z[i] = 0.f; }
}

// ---------------- edge pass 1: e = lrelu(a_src[s]+a_dst[d]); segment max ----------------
__global__ void edge_pass1(const int* __restrict__ ei, const float* __restrict__ a_src,
                           const float* __restrict__ a_dst, float* __restrict__ e_buf,
                           float* __restrict__ m) {
    int idx = blockIdx.x * blockDim.x + threadIdx.x;
    if (idx >= E_TOT * 4) return;
    int e = idx >> 2, hd = idx & 3;
    int s, d;
    if (e < N_EDGES) { s = ei[e]; d = ei[N_EDGES + e]; }
    else             { s = d = e - N_EDGES; }
    float v = a_src[s * 4 + hd] + a_dst[d * 4 + hd];
    v = (v > 0.f) ? v : NEG_SLOPE * v;
    e_buf[idx] = v;
    float* addr = &m[d * 4 + hd];
    if (v >= 0.f) atomicMax((int*)addr, __float_as_int(v));
    else          atomicMin((unsigned int*)addr, __float_as_uint(v));
}

// ---------------- edge pass 2: e = exp(e - m[dst]); z = segment sum ----------------
__global__ void edge_pass2(const int* __restrict__ ei, const float* __restrict__ m,
                           float* __restrict__ e_buf, float* __restrict__ z) {
    int idx = blockIdx.x * blockDim.x + threadIdx.x;
    if (idx >= E_TOT * 4) return;
    int e = idx >> 2, hd = idx & 3;
    int d = (e < N_EDGES) ? ei[N_EDGES + e] : (e - N_EDGES);
    float v = __expf(e_buf[idx] - m[d * 4 + hd]);
    e_buf[idx] = v;
    atomicAdd(&z[d * 4 + hd], v);
}

// ---------------- edge pass 3: scatter messages (one wave per edge) ----------------
__global__ void edge_pass3(const int* __restrict__ ei, const float* __restrict__ e_buf,
                           const float* __restrict__ z, const float* __restrict__ h,
                           float* __restrict__ conv) {
    int gid  = blockIdx.x * blockDim.x + threadIdx.x;
    int edge = gid >> 6;
    int lane = threadIdx.x & 63;
    if (edge >= E_TOT) return;
    int s, d;
    if (edge < N_EDGES) { s = ei[edge]; d = ei[N_EDGES + edge]; }
    else                { s = d = edge - N_EDGES; }
    #pragma unroll
    for (int hd = 0; hd < 4; ++hd) {
        float att = e_buf[edge * 4 + hd] / z[d * 4 + hd];
        float val = h[s * 256 + hd * 64 + lane] * att;
        atomicAdd(&conv[d * 256 + hd * 64 + lane], val);
    }
}

// ---------------- combine: res GEMV + elu + head-mix + GraphCON update ----------------
__global__ void combine_kernel(const float* __restrict__ conv, const float* __restrict__ conv_b,
                               const float* __restrict__ res_w, const float* __restrict__ res_b,
                               float* __restrict__ Y, float* __restrict__ X) {
    int n = blockIdx.x, t = threadIdx.x;   // 256 threads
    __shared__ float xrow[64];
    __shared__ float sval[256];
    if (t < 64) xrow[t] = X[n * 64 + t];
    __syncthreads();
    float acc = res_b[t];
    #pragma unroll 8
    for (int k = 0; k < 64; ++k) acc += xrow[k] * res_w[k * 256 + t];
    acc += conv[n * 256 + t] + conv_b[t];
    acc = (acc > 0.f) ? acc : (__expf(acc) - 1.f);   // elu
    sval[t] = acc;
    __syncthreads();
    if (t < 64) {
        // .reshape(N, 64, 4).mean(-1): groups of 4 consecutive flat elements
        float mixed = 0.25f * (sval[4*t] + sval[4*t+1] + sval[4*t+2] + sval[4*t+3]);
        float y = Y[n * 64 + t], xv = xrow[t];
        y  = y + 1.0f * (mixed - 1.0f * y - 1.0f * xv);  // DT=ALPHA=GAMMA=1
        xv = xv + 1.0f * y;
        Y[n * 64 + t] = y;
        X[n * 64 + t] = xv;
    }
}

// ---------------- decoder + pooling ----------------
__global__ void zero_out_kernel(float* __restrict__ out) {
    if (threadIdx.x < N_GRAPHS) out[threadIdx.x] = 0.f;
}

__global__ void decoder_kernel(const float* __restrict__ X, const float* __restrict__ dec_w,
                               const float* __restrict__ dec_b, const int* __restrict__ batch,
                               float* __restrict__ out) {
    int gid  = blockIdx.x * blockDim.x + threadIdx.x;
    int node = gid >> 6;
    int lane = threadIdx.x & 63;
    if (node >= N_NODES) return;
    float p = X[node * 64 + lane] * dec_w[lane];
    for (int off = 32; off >= 1; off >>= 1) p += __shfl_down(p, off);
    if (lane == 0) atomicAdd(&out[batch[node]], p + dec_b[0]);
}

extern "C" void kernel_launch(void* const* d_in, const int* in_sizes, int n_in,
                              void* d_out, int out_size, void* d_ws, size_t ws_size,
                              hipStream_t stream) {
    const float* x       = (const float*)d_in[0];
    const float* pos     = (const float*)d_in[1];
    const int*   ei      = (const int*)d_in[2];
    const int*   batch   = (const int*)d_in[3];
    const float* enc_w   = (const float*)d_in[4];
    const float* enc_b   = (const float*)d_in[5];
    const float* res_w   = (const float*)d_in[6];
    const float* res_b   = (const float*)d_in[7];
    const float* lin_w   = (const float*)d_in[8];
    const float* att_src = (const float*)d_in[9];
    const float* att_dst = (const float*)d_in[10];
    const float* conv_b  = (const float*)d_in[11];
    const float* dec_w   = (const float*)d_in[12];
    const float* dec_b   = (const float*)d_in[13];
    float* out = (float*)d_out;

    char* ws = (char*)d_ws;
    size_t off = 0;
    auto alloc = [&](size_t bytes) -> void* {
        void* p = ws + off;
        off += (bytes + 255) & ~size_t(255);
        return p;
    };
    float* Y     = (float*)alloc((size_t)N_NODES * 64 * sizeof(float));
    float* X     = (float*)alloc((size_t)N_NODES * 64 * sizeof(float));
    float* h     = (float*)alloc((size_t)N_NODES * HW * sizeof(float));
    float* conv  = (float*)alloc((size_t)N_NODES * HW * sizeof(float));
    float* a_src = (float*)alloc((size_t)N_NODES * NHEADS * sizeof(float));
    float* a_dst = (float*)alloc((size_t)N_NODES * NHEADS * sizeof(float));
    float* m     = (float*)alloc((size_t)N_NODES * NHEADS * sizeof(float));
    float* z     = (float*)alloc((size_t)N_NODES * NHEADS * sizeof(float));
    float* e_buf = (float*)alloc((size_t)E_TOT * NHEADS * sizeof(float));

    encoder_kernel<<<N_NODES, 64, 0, stream>>>(x, pos, enc_w, enc_b, Y, X);

    const int e4   = E_TOT * 4;
    const int eb   = (e4 + 255) / 256;
    const int ib   = (N_NODES * HW + 255) / 256;
    const int p3b  = (E_TOT * 64 + 255) / 256;

    for (int layer = 0; layer < 3; ++layer) {
        lin_kernel<<<N_NODES, 256, 0, stream>>>(X, lin_w, att_src, att_dst, h, a_src, a_dst);
        layer_init_kernel<<<ib, 256, 0, stream>>>(conv, m, z);
        edge_pass1<<<eb, 256, 0, stream>>>(ei, a_src, a_dst, e_buf, m);
        edge_pass2<<<eb, 256, 0, stream>>>(ei, m, e_buf, z);
        edge_pass3<<<p3b, 256, 0, stream>>>(ei, e_buf, z, h, conv);
        combine_kernel<<<N_NODES, 256, 0, stream>>>(conv, conv_b, res_w, res_b, Y, X);
    }

    zero_out_kernel<<<1, 64, 0, stream>>>(out);
    decoder_kernel<<<(N_NODES * 64 + 255) / 256, 256, 0, stream>>>(X, dec_w, dec_b, batch, out);
}

// Round 2
// 1607.080 us; speedup vs baseline: 2.1615x; 2.1615x over previous
//
#include <hip/hip_runtime.h>

#define N_NODES  50000
#define N_EDGES  800000
#define E_TOT    850000   // edges + self loops
#define N_GRAPHS 64
#define NHID     64
#define NHEADS   4
#define HW       256      // NHEADS*NHID
#define NEG_SLOPE 0.2f

// ---------------- encoder: Y = X = [x|pos] @ enc_w + enc_b ----------------
__global__ void encoder_kernel(const float* __restrict__ x, const float* __restrict__ pos,
                               const float* __restrict__ enc_w, const float* __restrict__ enc_b,
                               float* __restrict__ Y, float* __restrict__ X) {
    int n = blockIdx.x;
    int c = threadIdx.x;            // 0..63
    __shared__ float row[128];
    for (int k = c; k < 128; k += 64)
        row[k] = (k < 125) ? x[n * 125 + k] : pos[n * 3 + (k - 125)];
    __syncthreads();
    float acc = enc_b[c];
    #pragma unroll 8
    for (int k = 0; k < 128; ++k) acc += row[k] * enc_w[k * 64 + c];
    Y[n * 64 + c] = acc;
    X[n * 64 + c] = acc;
}

// ---------------- CSR build ----------------
__global__ void hist_kernel(const int* __restrict__ ei, int* __restrict__ counts) {
    int e = blockIdx.x * blockDim.x + threadIdx.x;
    if (e >= E_TOT) return;
    int d = (e < N_EDGES) ? ei[N_EDGES + e] : (e - N_EDGES);
    atomicAdd(&counts[d], 1);
}

__global__ void scan_kernel(const int* __restrict__ counts, int* __restrict__ row_ptr) {
    __shared__ int part[1024];
    int t = threadIdx.x;
    const int chunk = (N_NODES + 1023) / 1024;   // 49
    int base = t * chunk;
    int sum = 0;
    for (int i = 0; i < chunk; ++i) {
        int idx = base + i;
        if (idx < N_NODES) sum += counts[idx];
    }
    part[t] = sum;
    __syncthreads();
    for (int off = 1; off < 1024; off <<= 1) {
        int v = (t >= off) ? part[t - off] : 0;
        __syncthreads();
        part[t] += v;
        __syncthreads();
    }
    int run = (t == 0) ? 0 : part[t - 1];
    for (int i = 0; i < chunk; ++i) {
        int idx = base + i;
        if (idx < N_NODES) { row_ptr[idx] = run; run += counts[idx]; }
    }
    if (t == 1023) row_ptr[N_NODES] = part[1023];
}

__global__ void scatter_kernel(const int* __restrict__ ei, int* __restrict__ cursor,
                               int* __restrict__ col) {
    int e = blockIdx.x * blockDim.x + threadIdx.x;
    if (e >= E_TOT) return;
    int s, d;
    if (e < N_EDGES) { s = ei[e]; d = ei[N_EDGES + e]; }
    else             { s = d = e - N_EDGES; }
    int pos = atomicAdd(&cursor[d], 1);
    col[pos] = s;
}

// ---------------- h = X @ lin_w ; a_src/a_dst per head ----------------
__global__ void lin_kernel(const float* __restrict__ X, const float* __restrict__ lin_w,
                           const float* __restrict__ att_src, const float* __restrict__ att_dst,
                           float* __restrict__ h, float* __restrict__ a_src, float* __restrict__ a_dst) {
    int n = blockIdx.x;
    int t = threadIdx.x;            // 0..255
    __shared__ float xrow[64];
    if (t < 64) xrow[t] = X[n * 64 + t];
    __syncthreads();
    float acc = 0.f;
    #pragma unroll 8
    for (int k = 0; k < 64; ++k) acc += xrow[k] * lin_w[k * 256 + t];
    h[n * 256 + t] = acc;
    int head = t >> 6, c = t & 63;  // each wave (64 lanes) == one head
    float ps = acc * att_src[head * 64 + c];
    float pd = acc * att_dst[head * 64 + c];
    for (int off = 32; off >= 1; off >>= 1) {
        ps += __shfl_down(ps, off);
        pd += __shfl_down(pd, off);
    }
    if (c == 0) { a_src[n * 4 + head] = ps; a_dst[n * 4 + head] = pd; }
}

// ---------------- attention: one wave per dst node; softmax over incoming edges ----------------
__global__ void attn_kernel(const int* __restrict__ rp, const int* __restrict__ col,
                            const float* __restrict__ a_src, const float* __restrict__ a_dst,
                            float* __restrict__ att, float* __restrict__ zbuf) {
    int wid = (blockIdx.x * blockDim.x + threadIdx.x) >> 6;
    if (wid >= N_NODES) return;
    int lane = threadIdx.x & 63;
    int head = lane & 3, slot = lane >> 2;    // 16 edge-slots x 4 heads
    int base = rp[wid];
    int deg  = rp[wid + 1] - base;
    float ad = a_dst[wid * 4 + head];
    float mx = -3.0e38f;
    for (int j = slot; j < deg; j += 16) {
        int s = col[base + j];
        float v = a_src[s * 4 + head] + ad;
        v = (v > 0.f) ? v : NEG_SLOPE * v;
        att[(base + j) * 4 + head] = v;
        mx = fmaxf(mx, v);
    }
    #pragma unroll
    for (int off = 4; off < 64; off <<= 1) mx = fmaxf(mx, __shfl_xor(mx, off));
    float z = 0.f;
    for (int j = slot; j < deg; j += 16) {
        float v = __expf(att[(base + j) * 4 + head] - mx);
        att[(base + j) * 4 + head] = v;
        z += v;
    }
    #pragma unroll
    for (int off = 4; off < 64; off <<= 1) z += __shfl_xor(z, off);
    if (lane < 4) zbuf[wid * 4 + lane] = z;   // lane == head here
}

// ---------------- gather messages + residual + elu + head-mix + GraphCON update ----------------
__global__ void msg_combine_kernel(const int* __restrict__ rp, const int* __restrict__ col,
                                   const float* __restrict__ att, const float* __restrict__ zbuf,
                                   const float* __restrict__ h, const float* __restrict__ conv_b,
                                   const float* __restrict__ res_w, const float* __restrict__ res_b,
                                   float* __restrict__ Y, float* __restrict__ X) {
    int n = blockIdx.x;
    int t = threadIdx.x;            // 0..255; head = t>>6, channel = t&63
    int head = t >> 6;
    __shared__ float xrow[64];
    __shared__ float sval[256];
    __shared__ int   scol[64];
    __shared__ float satt[256];
    if (t < 64) xrow[t] = X[n * 64 + t];

    int base = rp[n];
    int deg  = rp[n + 1] - base;
    float invz = 1.f / zbuf[n * 4 + head];
    float acc = 0.f;
    for (int c0 = 0; c0 < deg; c0 += 64) {
        int cnt = min(64, deg - c0);
        __syncthreads();
        if (t < cnt)     scol[t] = col[base + c0 + t];
        if (t < cnt * 4) satt[t] = att[(base + c0) * 4 + t];
        __syncthreads();
        for (int j = 0; j < cnt; ++j)
            acc += satt[(j << 2) | head] * h[(size_t)scol[j] * 256 + t];
    }
    acc *= invz;

    __syncthreads();
    float r = res_b[t];
    #pragma unroll 8
    for (int k = 0; k < 64; ++k) r += xrow[k] * res_w[k * 256 + t];
    float v = acc + conv_b[t] + r;
    v = (v > 0.f) ? v : (__expf(v) - 1.f);   // elu
    sval[t] = v;
    __syncthreads();
    if (t < 64) {
        float mixed = 0.25f * (sval[4*t] + sval[4*t+1] + sval[4*t+2] + sval[4*t+3]);
        float y = Y[n * 64 + t], xv = xrow[t];
        y  = y + (mixed - y - xv);   // DT=ALPHA=GAMMA=1
        xv = xv + y;
        Y[n * 64 + t] = y;
        X[n * 64 + t] = xv;
    }
}

// ---------------- decoder + pooling ----------------
__global__ void decoder_kernel(const float* __restrict__ X, const float* __restrict__ dec_w,
                               const float* __restrict__ dec_b, const int* __restrict__ batch,
                               float* __restrict__ out) {
    int gid  = blockIdx.x * blockDim.x + threadIdx.x;
    int node = gid >> 6;
    int lane = threadIdx.x & 63;
    if (node >= N_NODES) return;
    float p = X[node * 64 + lane] * dec_w[lane];
    for (int off = 32; off >= 1; off >>= 1) p += __shfl_down(p, off);
    if (lane == 0) atomicAdd(&out[batch[node]], p + dec_b[0]);
}

extern "C" void kernel_launch(void* const* d_in, const int* in_sizes, int n_in,
                              void* d_out, int out_size, void* d_ws, size_t ws_size,
                              hipStream_t stream) {
    const float* x       = (const float*)d_in[0];
    const float* pos     = (const float*)d_in[1];
    const int*   ei      = (const int*)d_in[2];
    const int*   batch   = (const int*)d_in[3];
    const float* enc_w   = (const float*)d_in[4];
    const float* enc_b   = (const float*)d_in[5];
    const float* res_w   = (const float*)d_in[6];
    const float* res_b   = (const float*)d_in[7];
    const float* lin_w   = (const float*)d_in[8];
    const float* att_src = (const float*)d_in[9];
    const float* att_dst = (const float*)d_in[10];
    const float* conv_b  = (const float*)d_in[11];
    const float* dec_w   = (const float*)d_in[12];
    const float* dec_b   = (const float*)d_in[13];
    float* out = (float*)d_out;

    char* ws = (char*)d_ws;
    size_t off = 0;
    auto alloc = [&](size_t bytes) -> void* {
        void* p = ws + off;
        off += (bytes + 255) & ~size_t(255);
        return p;
    };
    float* Y      = (float*)alloc((size_t)N_NODES * 64 * sizeof(float));
    float* X      = (float*)alloc((size_t)N_NODES * 64 * sizeof(float));
    float* h      = (float*)alloc((size_t)N_NODES * HW * sizeof(float));
    float* a_src  = (float*)alloc((size_t)N_NODES * NHEADS * sizeof(float));
    float* a_dst  = (float*)alloc((size_t)N_NODES * NHEADS * sizeof(float));
    float* zbuf   = (float*)alloc((size_t)N_NODES * NHEADS * sizeof(float));
    float* att    = (float*)alloc((size_t)E_TOT * NHEADS * sizeof(float));
    int*   counts = (int*)alloc((size_t)N_NODES * sizeof(int));
    int*   row_ptr= (int*)alloc((size_t)(N_NODES + 1) * sizeof(int));
    int*   cursor = (int*)alloc((size_t)N_NODES * sizeof(int));
    int*   col    = (int*)alloc((size_t)E_TOT * sizeof(int));

    // ---- CSR build (dst is static; built each call for determinism) ----
    hipMemsetAsync(counts, 0, (size_t)N_NODES * sizeof(int), stream);
    const int eb = (E_TOT + 255) / 256;
    hist_kernel<<<eb, 256, 0, stream>>>(ei, counts);
    scan_kernel<<<1, 1024, 0, stream>>>(counts, row_ptr);
    hipMemcpyAsync(cursor, row_ptr, (size_t)N_NODES * sizeof(int),
                   hipMemcpyDeviceToDevice, stream);
    scatter_kernel<<<eb, 256, 0, stream>>>(ei, cursor, col);

    encoder_kernel<<<N_NODES, 64, 0, stream>>>(x, pos, enc_w, enc_b, Y, X);

    const int ab = (N_NODES * 64 + 255) / 256;   // one wave per node
    for (int layer = 0; layer < 3; ++layer) {
        lin_kernel<<<N_NODES, 256, 0, stream>>>(X, lin_w, att_src, att_dst, h, a_src, a_dst);
        attn_kernel<<<ab, 256, 0, stream>>>(row_ptr, col, a_src, a_dst, att, zbuf);
        msg_combine_kernel<<<N_NODES, 256, 0, stream>>>(row_ptr, col, att, zbuf, h,
                                                        conv_b, res_w, res_b, Y, X);
    }

    hipMemsetAsync(out, 0, N_GRAPHS * sizeof(float), stream);
    decoder_kernel<<<(N_NODES * 64 + 255) / 256, 256, 0, stream>>>(X, dec_w, dec_b, batch, out);
}

// Round 3
// 1245.847 us; speedup vs baseline: 2.7883x; 1.2899x over previous
//
#include <hip/hip_runtime.h>

#define N_NODES  50000
#define N_EDGES  800000
#define E_TOT    850000   // edges + self loops
#define N_GRAPHS 64
#define NHID     64
#define NHEADS   4
#define HW       256      // NHEADS*NHID
#define NEG_SLOPE 0.2f
#define DEC_BLOCKS 512

// ---------------- encoder: Y = X = [x|pos] @ enc_w + enc_b ----------------
__global__ void encoder_kernel(const float* __restrict__ x, const float* __restrict__ pos,
                               const float* __restrict__ enc_w, const float* __restrict__ enc_b,
                               float* __restrict__ Y, float* __restrict__ X) {
    int n = blockIdx.x;
    int c = threadIdx.x;            // 0..63
    __shared__ float row[128];
    for (int k = c; k < 128; k += 64)
        row[k] = (k < 125) ? x[n * 125 + k] : pos[n * 3 + (k - 125)];
    __syncthreads();
    float acc = enc_b[c];
    #pragma unroll 8
    for (int k = 0; k < 128; ++k) acc += row[k] * enc_w[k * 64 + c];
    Y[n * 64 + c] = acc;
    X[n * 64 + c] = acc;
}

// ---------------- CSR build ----------------
__global__ void hist_kernel(const int* __restrict__ ei, int* __restrict__ counts) {
    int e = blockIdx.x * blockDim.x + threadIdx.x;
    if (e >= E_TOT) return;
    int d = (e < N_EDGES) ? ei[N_EDGES + e] : (e - N_EDGES);
    atomicAdd(&counts[d], 1);
}

__global__ void scan_kernel(const int* __restrict__ counts, int* __restrict__ row_ptr) {
    __shared__ int part[1024];
    int t = threadIdx.x;
    const int chunk = (N_NODES + 1023) / 1024;   // 49
    int base = t * chunk;
    int sum = 0;
    for (int i = 0; i < chunk; ++i) {
        int idx = base + i;
        if (idx < N_NODES) sum += counts[idx];
    }
    part[t] = sum;
    __syncthreads();
    for (int off = 1; off < 1024; off <<= 1) {
        int v = (t >= off) ? part[t - off] : 0;
        __syncthreads();
        part[t] += v;
        __syncthreads();
    }
    int run = (t == 0) ? 0 : part[t - 1];
    for (int i = 0; i < chunk; ++i) {
        int idx = base + i;
        if (idx < N_NODES) { row_ptr[idx] = run; run += counts[idx]; }
    }
    if (t == 1023) row_ptr[N_NODES] = part[1023];
}

__global__ void scatter_kernel(const int* __restrict__ ei, int* __restrict__ cursor,
                               int* __restrict__ col) {
    int e = blockIdx.x * blockDim.x + threadIdx.x;
    if (e >= E_TOT) return;
    int s, d;
    if (e < N_EDGES) { s = ei[e]; d = ei[N_EDGES + e]; }
    else             { s = d = e - N_EDGES; }
    int pos = atomicAdd(&cursor[d], 1);
    col[pos] = s;
}

// ---------------- h = X @ lin_w ; a_src/a_dst per head ----------------
__global__ void lin_kernel(const float* __restrict__ X, const float* __restrict__ lin_w,
                           const float* __restrict__ att_src, const float* __restrict__ att_dst,
                           float* __restrict__ h, float* __restrict__ a_src, float* __restrict__ a_dst) {
    int n = blockIdx.x;
    int t = threadIdx.x;            // 0..255
    __shared__ float xrow[64];
    if (t < 64) xrow[t] = X[n * 64 + t];
    __syncthreads();
    float acc = 0.f;
    #pragma unroll 8
    for (int k = 0; k < 64; ++k) acc += xrow[k] * lin_w[k * 256 + t];
    h[n * 256 + t] = acc;
    int head = t >> 6, c = t & 63;  // each wave (64 lanes) == one head
    float ps = acc * att_src[head * 64 + c];
    float pd = acc * att_dst[head * 64 + c];
    for (int off = 32; off >= 1; off >>= 1) {
        ps += __shfl_down(ps, off);
        pd += __shfl_down(pd, off);
    }
    if (c == 0) { a_src[n * 4 + head] = ps; a_dst[n * 4 + head] = pd; }
}

// ---------------- attention: one wave per dst node; softmax over incoming edges ----------------
__global__ void attn_kernel(const int* __restrict__ rp, const int* __restrict__ col,
                            const float* __restrict__ a_src, const float* __restrict__ a_dst,
                            float* __restrict__ att, float* __restrict__ zbuf) {
    int wid = (blockIdx.x * blockDim.x + threadIdx.x) >> 6;
    if (wid >= N_NODES) return;
    int lane = threadIdx.x & 63;
    int head = lane & 3, slot = lane >> 2;    // 16 edge-slots x 4 heads
    int base = rp[wid];
    int deg  = rp[wid + 1] - base;
    float ad = a_dst[wid * 4 + head];
    float mx = -3.0e38f;
    for (int j = slot; j < deg; j += 16) {
        int s = col[base + j];
        float v = a_src[s * 4 + head] + ad;
        v = (v > 0.f) ? v : NEG_SLOPE * v;
        att[(base + j) * 4 + head] = v;
        mx = fmaxf(mx, v);
    }
    #pragma unroll
    for (int off = 4; off < 64; off <<= 1) mx = fmaxf(mx, __shfl_xor(mx, off));
    float z = 0.f;
    for (int j = slot; j < deg; j += 16) {
        float v = __expf(att[(base + j) * 4 + head] - mx);
        att[(base + j) * 4 + head] = v;
        z += v;
    }
    #pragma unroll
    for (int off = 4; off < 64; off <<= 1) z += __shfl_xor(z, off);
    if (lane < 4) zbuf[wid * 4 + lane] = z;   // lane == head here
}

// ---------------- gather messages + residual + elu + head-mix + GraphCON update ----------------
__global__ void msg_combine_kernel(const int* __restrict__ rp, const int* __restrict__ col,
                                   const float* __restrict__ att, const float* __restrict__ zbuf,
                                   const float* __restrict__ h, const float* __restrict__ conv_b,
                                   const float* __restrict__ res_w, const float* __restrict__ res_b,
                                   float* __restrict__ Y, float* __restrict__ X) {
    int n = blockIdx.x;
    int t = threadIdx.x;            // 0..255; head = t>>6, channel = t&63
    int head = t >> 6;
    __shared__ float xrow[64];
    __shared__ float sval[256];
    __shared__ int   scol[64];
    __shared__ float satt[256];
    if (t < 64) xrow[t] = X[n * 64 + t];

    int base = rp[n];
    int deg  = rp[n + 1] - base;
    float invz = 1.f / zbuf[n * 4 + head];
    float acc = 0.f;
    for (int c0 = 0; c0 < deg; c0 += 64) {
        int cnt = min(64, deg - c0);
        __syncthreads();
        if (t < cnt)     scol[t] = col[base + c0 + t];
        if (t < cnt * 4) satt[t] = att[(base + c0) * 4 + t];
        __syncthreads();
        for (int j = 0; j < cnt; ++j)
            acc += satt[(j << 2) | head] * h[(size_t)scol[j] * 256 + t];
    }
    acc *= invz;

    __syncthreads();
    float r = res_b[t];
    #pragma unroll 8
    for (int k = 0; k < 64; ++k) r += xrow[k] * res_w[k * 256 + t];
    float v = acc + conv_b[t] + r;
    v = (v > 0.f) ? v : (__expf(v) - 1.f);   // elu
    sval[t] = v;
    __syncthreads();
    if (t < 64) {
        float mixed = 0.25f * (sval[4*t] + sval[4*t+1] + sval[4*t+2] + sval[4*t+3]);
        float y = Y[n * 64 + t], xv = xrow[t];
        y  = y + (mixed - y - xv);   // DT=ALPHA=GAMMA=1
        xv = xv + y;
        Y[n * 64 + t] = y;
        X[n * 64 + t] = xv;
    }
}

// ---------------- decoder: per-block partials (no global atomics) ----------------
__global__ void decoder_partial_kernel(const float* __restrict__ X, const float* __restrict__ dec_w,
                                       const float* __restrict__ dec_b, const int* __restrict__ batch,
                                       float* __restrict__ partials) {
    __shared__ float sg[N_GRAPHS];
    int t = threadIdx.x;                      // 256 threads = 4 waves
    if (t < N_GRAPHS) sg[t] = 0.f;
    __syncthreads();
    int lane = t & 63;
    int wave = t >> 6;
    const int npb = (N_NODES + DEC_BLOCKS - 1) / DEC_BLOCKS;   // 98
    int start = blockIdx.x * npb;
    int end   = min(start + npb, N_NODES);
    float dw = dec_w[lane];
    float db = dec_b[0];
    for (int n = start + wave; n < end; n += 4) {
        float p = X[n * 64 + lane] * dw;
        #pragma unroll
        for (int off = 32; off >= 1; off >>= 1) p += __shfl_down(p, off);
        if (lane == 0) atomicAdd(&sg[batch[n]], p + db);
    }
    __syncthreads();
    if (t < N_GRAPHS) partials[blockIdx.x * N_GRAPHS + t] = sg[t];
}

__global__ void decoder_reduce_kernel(const float* __restrict__ partials, float* __restrict__ out) {
    // 256 threads: thread (g = t&63, j = t>>6) sums blocks j*128..(j+1)*128
    __shared__ float red[256];
    int t = threadIdx.x;
    int g = t & 63, j = t >> 6;
    float s = 0.f;
    for (int b = j * (DEC_BLOCKS / 4); b < (j + 1) * (DEC_BLOCKS / 4); ++b)
        s += partials[b * N_GRAPHS + g];
    red[t] = s;
    __syncthreads();
    if (t < 64) out[g] = red[g] + red[64 + g] + red[128 + g] + red[192 + g];
}

extern "C" void kernel_launch(void* const* d_in, const int* in_sizes, int n_in,
                              void* d_out, int out_size, void* d_ws, size_t ws_size,
                              hipStream_t stream) {
    const float* x       = (const float*)d_in[0];
    const float* pos     = (const float*)d_in[1];
    const int*   ei      = (const int*)d_in[2];
    const int*   batch   = (const int*)d_in[3];
    const float* enc_w   = (const float*)d_in[4];
    const float* enc_b   = (const float*)d_in[5];
    const float* res_w   = (const float*)d_in[6];
    const float* res_b   = (const float*)d_in[7];
    const float* lin_w   = (const float*)d_in[8];
    const float* att_src = (const float*)d_in[9];
    const float* att_dst = (const float*)d_in[10];
    const float* conv_b  = (const float*)d_in[11];
    const float* dec_w   = (const float*)d_in[12];
    const float* dec_b   = (const float*)d_in[13];
    float* out = (float*)d_out;

    char* ws = (char*)d_ws;
    size_t off = 0;
    auto alloc = [&](size_t bytes) -> void* {
        void* p = ws + off;
        off += (bytes + 255) & ~size_t(255);
        return p;
    };
    float* Y       = (float*)alloc((size_t)N_NODES * 64 * sizeof(float));
    float* X       = (float*)alloc((size_t)N_NODES * 64 * sizeof(float));
    float* h       = (float*)alloc((size_t)N_NODES * HW * sizeof(float));
    float* a_src   = (float*)alloc((size_t)N_NODES * NHEADS * sizeof(float));
    float* a_dst   = (float*)alloc((size_t)N_NODES * NHEADS * sizeof(float));
    float* zbuf    = (float*)alloc((size_t)N_NODES * NHEADS * sizeof(float));
    float* att     = (float*)alloc((size_t)E_TOT * NHEADS * sizeof(float));
    float* partials= (float*)alloc((size_t)DEC_BLOCKS * N_GRAPHS * sizeof(float));
    int*   counts  = (int*)alloc((size_t)N_NODES * sizeof(int));
    int*   row_ptr = (int*)alloc((size_t)(N_NODES + 1) * sizeof(int));
    int*   cursor  = (int*)alloc((size_t)N_NODES * sizeof(int));
    int*   col     = (int*)alloc((size_t)E_TOT * sizeof(int));

    // ---- CSR build (dst is static; built each call for determinism) ----
    hipMemsetAsync(counts, 0, (size_t)N_NODES * sizeof(int), stream);
    const int eb = (E_TOT + 255) / 256;
    hist_kernel<<<eb, 256, 0, stream>>>(ei, counts);
    scan_kernel<<<1, 1024, 0, stream>>>(counts, row_ptr);
    hipMemcpyAsync(cursor, row_ptr, (size_t)N_NODES * sizeof(int),
                   hipMemcpyDeviceToDevice, stream);
    scatter_kernel<<<eb, 256, 0, stream>>>(ei, cursor, col);

    encoder_kernel<<<N_NODES, 64, 0, stream>>>(x, pos, enc_w, enc_b, Y, X);

    const int ab = (N_NODES * 64 + 255) / 256;   // one wave per node
    for (int layer = 0; layer < 3; ++layer) {
        lin_kernel<<<N_NODES, 256, 0, stream>>>(X, lin_w, att_src, att_dst, h, a_src, a_dst);
        attn_kernel<<<ab, 256, 0, stream>>>(row_ptr, col, a_src, a_dst, att, zbuf);
        msg_combine_kernel<<<N_NODES, 256, 0, stream>>>(row_ptr, col, att, zbuf, h,
                                                        conv_b, res_w, res_b, Y, X);
    }

    decoder_partial_kernel<<<DEC_BLOCKS, 256, 0, stream>>>(X, dec_w, dec_b, batch, partials);
    decoder_reduce_kernel<<<1, 256, 0, stream>>>(partials, out);
}

// Round 4
// 1202.152 us; speedup vs baseline: 2.8896x; 1.0363x over previous
//
#include <hip/hip_runtime.h>
#include <hip/hip_bf16.h>

#define N_NODES  50000
#define N_EDGES  800000
#define E_TOT    850000   // edges + self loops
#define N_GRAPHS 64
#define NHID     64
#define NHEADS   4
#define HW       256      // NHEADS*NHID
#define NEG_SLOPE 0.2f
#define DEC_BLOCKS 512

// ---------------- encoder: Y = X = [x|pos] @ enc_w + enc_b ----------------
__global__ void encoder_kernel(const float* __restrict__ x, const float* __restrict__ pos,
                               const float* __restrict__ enc_w, const float* __restrict__ enc_b,
                               float* __restrict__ Y, float* __restrict__ X) {
    int n = blockIdx.x;
    int c = threadIdx.x;            // 0..63
    __shared__ float row[128];
    for (int k = c; k < 128; k += 64)
        row[k] = (k < 125) ? x[n * 125 + k] : pos[n * 3 + (k - 125)];
    __syncthreads();
    float acc = enc_b[c];
    #pragma unroll 8
    for (int k = 0; k < 128; ++k) acc += row[k] * enc_w[k * 64 + c];
    Y[n * 64 + c] = acc;
    X[n * 64 + c] = acc;
}

// ---------------- CSR build ----------------
__global__ void hist_kernel(const int* __restrict__ ei, int* __restrict__ counts) {
    int e = blockIdx.x * blockDim.x + threadIdx.x;
    if (e >= E_TOT) return;
    int d = (e < N_EDGES) ? ei[N_EDGES + e] : (e - N_EDGES);
    atomicAdd(&counts[d], 1);
}

__global__ void scan_kernel(const int* __restrict__ counts, int* __restrict__ row_ptr) {
    __shared__ int part[1024];
    int t = threadIdx.x;
    const int chunk = (N_NODES + 1023) / 1024;   // 49
    int base = t * chunk;
    int sum = 0;
    for (int i = 0; i < chunk; ++i) {
        int idx = base + i;
        if (idx < N_NODES) sum += counts[idx];
    }
    part[t] = sum;
    __syncthreads();
    for (int off = 1; off < 1024; off <<= 1) {
        int v = (t >= off) ? part[t - off] : 0;
        __syncthreads();
        part[t] += v;
        __syncthreads();
    }
    int run = (t == 0) ? 0 : part[t - 1];
    for (int i = 0; i < chunk; ++i) {
        int idx = base + i;
        if (idx < N_NODES) { row_ptr[idx] = run; run += counts[idx]; }
    }
    if (t == 1023) row_ptr[N_NODES] = part[1023];
}

__global__ void scatter_kernel(const int* __restrict__ ei, int* __restrict__ cursor,
                               int* __restrict__ col) {
    int e = blockIdx.x * blockDim.x + threadIdx.x;
    if (e >= E_TOT) return;
    int s, d;
    if (e < N_EDGES) { s = ei[e]; d = ei[N_EDGES + e]; }
    else             { s = d = e - N_EDGES; }
    int pos = atomicAdd(&cursor[d], 1);
    col[pos] = s;
}

// ---------------- h = X @ lin_w (bf16 out); a_src/a_dst per head ----------------
__global__ void lin_kernel(const float* __restrict__ X, const float* __restrict__ lin_w,
                           const float* __restrict__ att_src, const float* __restrict__ att_dst,
                           __hip_bfloat16* __restrict__ h, float* __restrict__ a_src,
                           float* __restrict__ a_dst) {
    int n = blockIdx.x;
    int t = threadIdx.x;            // 0..255
    __shared__ float xrow[64];
    if (t < 64) xrow[t] = X[n * 64 + t];
    __syncthreads();
    float acc = 0.f;
    #pragma unroll 8
    for (int k = 0; k < 64; ++k) acc += xrow[k] * lin_w[k * 256 + t];
    h[n * 256 + t] = __float2bfloat16(acc);   // logits below use fp32 acc (pre-rounding)
    int head = t >> 6, c = t & 63;  // each wave (64 lanes) == one head
    float ps = acc * att_src[head * 64 + c];
    float pd = acc * att_dst[head * 64 + c];
    for (int off = 32; off >= 1; off >>= 1) {
        ps += __shfl_down(ps, off);
        pd += __shfl_down(pd, off);
    }
    if (c == 0) { a_src[n * 4 + head] = ps; a_dst[n * 4 + head] = pd; }
}

// ---------------- attention: one wave per dst node; softmax over incoming edges ----------------
__global__ void attn_kernel(const int* __restrict__ rp, const int* __restrict__ col,
                            const float* __restrict__ a_src, const float* __restrict__ a_dst,
                            float* __restrict__ att, float* __restrict__ zbuf) {
    int wid = (blockIdx.x * blockDim.x + threadIdx.x) >> 6;
    if (wid >= N_NODES) return;
    int lane = threadIdx.x & 63;
    int head = lane & 3, slot = lane >> 2;    // 16 edge-slots x 4 heads
    int base = rp[wid];
    int deg  = rp[wid + 1] - base;
    float ad = a_dst[wid * 4 + head];
    float mx = -3.0e38f;
    for (int j = slot; j < deg; j += 16) {
        int s = col[base + j];
        float v = a_src[s * 4 + head] + ad;
        v = (v > 0.f) ? v : NEG_SLOPE * v;
        att[(base + j) * 4 + head] = v;
        mx = fmaxf(mx, v);
    }
    #pragma unroll
    for (int off = 4; off < 64; off <<= 1) mx = fmaxf(mx, __shfl_xor(mx, off));
    float z = 0.f;
    for (int j = slot; j < deg; j += 16) {
        float v = __expf(att[(base + j) * 4 + head] - mx);
        att[(base + j) * 4 + head] = v;
        z += v;
    }
    #pragma unroll
    for (int off = 4; off < 64; off <<= 1) z += __shfl_xor(z, off);
    if (lane < 4) zbuf[wid * 4 + lane] = z;   // lane == head here
}

// ---------------- gather messages + residual + elu + head-mix + GraphCON update ----------------
__global__ void msg_combine_kernel(const int* __restrict__ rp, const int* __restrict__ col,
                                   const float* __restrict__ att, const float* __restrict__ zbuf,
                                   const __hip_bfloat16* __restrict__ h,
                                   const float* __restrict__ conv_b,
                                   const float* __restrict__ res_w, const float* __restrict__ res_b,
                                   float* __restrict__ Y, float* __restrict__ X) {
    int n = blockIdx.x;
    int t = threadIdx.x;            // 0..255; head = t>>6, channel = t&63
    int head = t >> 6;
    __shared__ float xrow[64];
    __shared__ float sval[256];
    __shared__ int   scol[64];
    __shared__ float satt[256];
    if (t < 64) xrow[t] = X[n * 64 + t];

    int base = rp[n];
    int deg  = rp[n + 1] - base;
    float invz = 1.f / zbuf[n * 4 + head];
    float acc = 0.f;
    for (int c0 = 0; c0 < deg; c0 += 64) {
        int cnt = min(64, deg - c0);
        __syncthreads();
        if (t < cnt)     scol[t] = col[base + c0 + t];
        if (t < cnt * 4) satt[t] = att[(base + c0) * 4 + t];
        __syncthreads();
        for (int j = 0; j < cnt; ++j)
            acc += satt[(j << 2) | head] * __bfloat162float(h[(size_t)scol[j] * 256 + t]);
    }
    acc *= invz;

    __syncthreads();
    float r = res_b[t];
    #pragma unroll 8
    for (int k = 0; k < 64; ++k) r += xrow[k] * res_w[k * 256 + t];
    float v = acc + conv_b[t] + r;
    v = (v > 0.f) ? v : (__expf(v) - 1.f);   // elu
    sval[t] = v;
    __syncthreads();
    if (t < 64) {
        float mixed = 0.25f * (sval[4*t] + sval[4*t+1] + sval[4*t+2] + sval[4*t+3]);
        float y = Y[n * 64 + t], xv = xrow[t];
        y  = y + (mixed - y - xv);   // DT=ALPHA=GAMMA=1
        xv = xv + y;
        Y[n * 64 + t] = y;
        X[n * 64 + t] = xv;
    }
}

// ---------------- decoder: per-block partials (no global atomics) ----------------
__global__ void decoder_partial_kernel(const float* __restrict__ X, const float* __restrict__ dec_w,
                                       const float* __restrict__ dec_b, const int* __restrict__ batch,
                                       float* __restrict__ partials) {
    __shared__ float sg[N_GRAPHS];
    int t = threadIdx.x;                      // 256 threads = 4 waves
    if (t < N_GRAPHS) sg[t] = 0.f;
    __syncthreads();
    int lane = t & 63;
    int wave = t >> 6;
    const int npb = (N_NODES + DEC_BLOCKS - 1) / DEC_BLOCKS;   // 98
    int start = blockIdx.x * npb;
    int end   = min(start + npb, N_NODES);
    float dw = dec_w[lane];
    float db = dec_b[0];
    for (int n = start + wave; n < end; n += 4) {
        float p = X[n * 64 + lane] * dw;
        #pragma unroll
        for (int off = 32; off >= 1; off >>= 1) p += __shfl_down(p, off);
        if (lane == 0) atomicAdd(&sg[batch[n]], p + db);
    }
    __syncthreads();
    if (t < N_GRAPHS) partials[blockIdx.x * N_GRAPHS + t] = sg[t];
}

__global__ void decoder_reduce_kernel(const float* __restrict__ partials, float* __restrict__ out) {
    __shared__ float red[256];
    int t = threadIdx.x;
    int g = t & 63, j = t >> 6;
    float s = 0.f;
    for (int b = j * (DEC_BLOCKS / 4); b < (j + 1) * (DEC_BLOCKS / 4); ++b)
        s += partials[b * N_GRAPHS + g];
    red[t] = s;
    __syncthreads();
    if (t < 64) out[g] = red[g] + red[64 + g] + red[128 + g] + red[192 + g];
}

extern "C" void kernel_launch(void* const* d_in, const int* in_sizes, int n_in,
                              void* d_out, int out_size, void* d_ws, size_t ws_size,
                              hipStream_t stream) {
    const float* x       = (const float*)d_in[0];
    const float* pos     = (const float*)d_in[1];
    const int*   ei      = (const int*)d_in[2];
    const int*   batch   = (const int*)d_in[3];
    const float* enc_w   = (const float*)d_in[4];
    const float* enc_b   = (const float*)d_in[5];
    const float* res_w   = (const float*)d_in[6];
    const float* res_b   = (const float*)d_in[7];
    const float* lin_w   = (const float*)d_in[8];
    const float* att_src = (const float*)d_in[9];
    const float* att_dst = (const float*)d_in[10];
    const float* conv_b  = (const float*)d_in[11];
    const float* dec_w   = (const float*)d_in[12];
    const float* dec_b   = (const float*)d_in[13];
    float* out = (float*)d_out;

    char* ws = (char*)d_ws;
    size_t off = 0;
    auto alloc = [&](size_t bytes) -> void* {
        void* p = ws + off;
        off += (bytes + 255) & ~size_t(255);
        return p;
    };
    float* Y       = (float*)alloc((size_t)N_NODES * 64 * sizeof(float));
    float* X       = (float*)alloc((size_t)N_NODES * 64 * sizeof(float));
    __hip_bfloat16* h = (__hip_bfloat16*)alloc((size_t)N_NODES * HW * sizeof(__hip_bfloat16));
    float* a_src   = (float*)alloc((size_t)N_NODES * NHEADS * sizeof(float));
    float* a_dst   = (float*)alloc((size_t)N_NODES * NHEADS * sizeof(float));
    float* zbuf    = (float*)alloc((size_t)N_NODES * NHEADS * sizeof(float));
    float* att     = (float*)alloc((size_t)E_TOT * NHEADS * sizeof(float));
    float* partials= (float*)alloc((size_t)DEC_BLOCKS * N_GRAPHS * sizeof(float));
    int*   counts  = (int*)alloc((size_t)N_NODES * sizeof(int));
    int*   row_ptr = (int*)alloc((size_t)(N_NODES + 1) * sizeof(int));
    int*   cursor  = (int*)alloc((size_t)N_NODES * sizeof(int));
    int*   col     = (int*)alloc((size_t)E_TOT * sizeof(int));

    // ---- CSR build (dst is static; built each call for determinism) ----
    hipMemsetAsync(counts, 0, (size_t)N_NODES * sizeof(int), stream);
    const int eb = (E_TOT + 255) / 256;
    hist_kernel<<<eb, 256, 0, stream>>>(ei, counts);
    scan_kernel<<<1, 1024, 0, stream>>>(counts, row_ptr);
    hipMemcpyAsync(cursor, row_ptr, (size_t)N_NODES * sizeof(int),
                   hipMemcpyDeviceToDevice, stream);
    scatter_kernel<<<eb, 256, 0, stream>>>(ei, cursor, col);

    encoder_kernel<<<N_NODES, 64, 0, stream>>>(x, pos, enc_w, enc_b, Y, X);

    const int ab = (N_NODES * 64 + 255) / 256;   // one wave per node
    for (int layer = 0; layer < 3; ++layer) {
        lin_kernel<<<N_NODES, 256, 0, stream>>>(X, lin_w, att_src, att_dst, h, a_src, a_dst);
        attn_kernel<<<ab, 256, 0, stream>>>(row_ptr, col, a_src, a_dst, att, zbuf);
        msg_combine_kernel<<<N_NODES, 256, 0, stream>>>(row_ptr, col, att, zbuf, h,
                                                        conv_b, res_w, res_b, Y, X);
    }

    decoder_partial_kernel<<<DEC_BLOCKS, 256, 0, stream>>>(X, dec_w, dec_b, batch, partials);
    decoder_reduce_kernel<<<1, 256, 0, stream>>>(partials, out);
}

// Round 5
// 1123.783 us; speedup vs baseline: 3.0911x; 1.0697x over previous
//
#include <hip/hip_runtime.h>
#include <hip/hip_bf16.h>

#define N_NODES  50000
#define N_EDGES  800000
#define E_TOT    850000   // edges + self loops
#define N_GRAPHS 64
#define NHID     64
#define NHEADS   4
#define HW       256      // NHEADS*NHID
#define NEG_SLOPE 0.2f
#define DEC_BLOCKS 512

__device__ __forceinline__ float bf2f(unsigned short u) {
    return __uint_as_float(((unsigned)u) << 16);
}

// ---------------- encoder: Y = X = [x|pos] @ enc_w + enc_b ----------------
__global__ void encoder_kernel(const float* __restrict__ x, const float* __restrict__ pos,
                               const float* __restrict__ enc_w, const float* __restrict__ enc_b,
                               float* __restrict__ Y, float* __restrict__ X) {
    int n = blockIdx.x;
    int c = threadIdx.x;            // 0..63
    __shared__ float row[128];
    for (int k = c; k < 128; k += 64)
        row[k] = (k < 125) ? x[n * 125 + k] : pos[n * 3 + (k - 125)];
    __syncthreads();
    float acc = enc_b[c];
    #pragma unroll 8
    for (int k = 0; k < 128; ++k) acc += row[k] * enc_w[k * 64 + c];
    Y[n * 64 + c] = acc;
    X[n * 64 + c] = acc;
}

// ---------------- CSR build ----------------
__global__ void hist_kernel(const int* __restrict__ ei, int* __restrict__ counts) {
    int e = blockIdx.x * blockDim.x + threadIdx.x;
    if (e >= E_TOT) return;
    int d = (e < N_EDGES) ? ei[N_EDGES + e] : (e - N_EDGES);
    atomicAdd(&counts[d], 1);
}

__global__ void scan_kernel(const int* __restrict__ counts, int* __restrict__ row_ptr) {
    __shared__ int part[1024];
    int t = threadIdx.x;
    const int chunk = (N_NODES + 1023) / 1024;   // 49
    int base = t * chunk;
    int sum = 0;
    for (int i = 0; i < chunk; ++i) {
        int idx = base + i;
        if (idx < N_NODES) sum += counts[idx];
    }
    part[t] = sum;
    __syncthreads();
    for (int off = 1; off < 1024; off <<= 1) {
        int v = (t >= off) ? part[t - off] : 0;
        __syncthreads();
        part[t] += v;
        __syncthreads();
    }
    int run = (t == 0) ? 0 : part[t - 1];
    for (int i = 0; i < chunk; ++i) {
        int idx = base + i;
        if (idx < N_NODES) { row_ptr[idx] = run; run += counts[idx]; }
    }
    if (t == 1023) row_ptr[N_NODES] = part[1023];
}

__global__ void scatter_kernel(const int* __restrict__ ei, int* __restrict__ cursor,
                               int* __restrict__ col) {
    int e = blockIdx.x * blockDim.x + threadIdx.x;
    if (e >= E_TOT) return;
    int s, d;
    if (e < N_EDGES) { s = ei[e]; d = ei[N_EDGES + e]; }
    else             { s = d = e - N_EDGES; }
    int pos = atomicAdd(&cursor[d], 1);
    col[pos] = s;
}

// ---------------- h = X @ lin_w (bf16 out); a_src/a_dst per head ----------------
__global__ void lin_kernel(const float* __restrict__ X, const float* __restrict__ lin_w,
                           const float* __restrict__ att_src, const float* __restrict__ att_dst,
                           __hip_bfloat16* __restrict__ h, float* __restrict__ a_src,
                           float* __restrict__ a_dst) {
    int n = blockIdx.x;
    int t = threadIdx.x;            // 0..255
    __shared__ float xrow[64];
    if (t < 64) xrow[t] = X[n * 64 + t];
    __syncthreads();
    float acc = 0.f;
    #pragma unroll 8
    for (int k = 0; k < 64; ++k) acc += xrow[k] * lin_w[k * 256 + t];
    h[n * 256 + t] = __float2bfloat16(acc);   // logits below use fp32 acc (pre-rounding)
    int head = t >> 6, c = t & 63;  // each wave (64 lanes) == one head
    float ps = acc * att_src[head * 64 + c];
    float pd = acc * att_dst[head * 64 + c];
    for (int off = 32; off >= 1; off >>= 1) {
        ps += __shfl_down(ps, off);
        pd += __shfl_down(pd, off);
    }
    if (c == 0) { a_src[n * 4 + head] = ps; a_dst[n * 4 + head] = pd; }
}

// ---------------- attention: one wave per dst node; softmax over incoming edges ----------------
__global__ void attn_kernel(const int* __restrict__ rp, const int* __restrict__ col,
                            const float* __restrict__ a_src, const float* __restrict__ a_dst,
                            float* __restrict__ att, float* __restrict__ zbuf) {
    int wid = (blockIdx.x * blockDim.x + threadIdx.x) >> 6;
    if (wid >= N_NODES) return;
    int lane = threadIdx.x & 63;
    int head = lane & 3, slot = lane >> 2;    // 16 edge-slots x 4 heads
    int base = rp[wid];
    int deg  = rp[wid + 1] - base;
    float ad = a_dst[wid * 4 + head];
    float mx = -3.0e38f;
    for (int j = slot; j < deg; j += 16) {
        int s = col[base + j];
        float v = a_src[s * 4 + head] + ad;
        v = (v > 0.f) ? v : NEG_SLOPE * v;
        att[(base + j) * 4 + head] = v;
        mx = fmaxf(mx, v);
    }
    #pragma unroll
    for (int off = 4; off < 64; off <<= 1) mx = fmaxf(mx, __shfl_xor(mx, off));
    float z = 0.f;
    for (int j = slot; j < deg; j += 16) {
        float v = __expf(att[(base + j) * 4 + head] - mx);
        att[(base + j) * 4 + head] = v;
        z += v;
    }
    #pragma unroll
    for (int off = 4; off < 64; off <<= 1) z += __shfl_xor(z, off);
    if (lane < 4) zbuf[wid * 4 + lane] = z;   // lane == head here
}

// ---- gather + residual + elu + head-mix + update: ONE WAVE per node, lane owns 4 channels ----
__global__ void msg_combine_kernel(const int* __restrict__ rp, const int* __restrict__ col,
                                   const float* __restrict__ att, const float* __restrict__ zbuf,
                                   const __hip_bfloat16* __restrict__ h,
                                   const float* __restrict__ conv_b,
                                   const float* __restrict__ res_w, const float* __restrict__ res_b,
                                   float* __restrict__ Y, float* __restrict__ X) {
    int n = (blockIdx.x * blockDim.x + threadIdx.x) >> 6;
    if (n >= N_NODES) return;
    int lane = threadIdx.x & 63;
    int head = lane >> 4;               // channels 4*lane..4*lane+3 all in this head
    int base = rp[n];
    int deg  = rp[n + 1] - base;
    float invz = 1.f / zbuf[n * 4 + head];
    const ushort* hp = (const ushort*)h;

    float a0 = 0.f, a1 = 0.f, a2 = 0.f, a3 = 0.f;
    int j = 0;
    for (; j + 2 <= deg; j += 2) {       // two gathers in flight
        int e0 = base + j, e1 = base + j + 1;
        int s0 = col[e0], s1 = col[e1];
        float w0 = att[e0 * 4 + head];
        float w1 = att[e1 * 4 + head];
        ushort4 v0 = *(const ushort4*)(hp + (size_t)s0 * 256 + lane * 4);
        ushort4 v1 = *(const ushort4*)(hp + (size_t)s1 * 256 + lane * 4);
        a0 += w0 * bf2f(v0.x); a1 += w0 * bf2f(v0.y);
        a2 += w0 * bf2f(v0.z); a3 += w0 * bf2f(v0.w);
        a0 += w1 * bf2f(v1.x); a1 += w1 * bf2f(v1.y);
        a2 += w1 * bf2f(v1.z); a3 += w1 * bf2f(v1.w);
    }
    if (j < deg) {
        int e0 = base + j;
        int s0 = col[e0];
        float w0 = att[e0 * 4 + head];
        ushort4 v0 = *(const ushort4*)(hp + (size_t)s0 * 256 + lane * 4);
        a0 += w0 * bf2f(v0.x); a1 += w0 * bf2f(v0.y);
        a2 += w0 * bf2f(v0.z); a3 += w0 * bf2f(v0.w);
    }
    a0 *= invz; a1 *= invz; a2 *= invz; a3 *= invz;

    // residual GEMV for this lane's 4 channels; X row broadcast via shfl
    float xv = X[n * 64 + lane];
    float4 r = ((const float4*)res_b)[lane];
    const float4* rw = (const float4*)res_w;
    #pragma unroll 8
    for (int k = 0; k < 64; ++k) {
        float xk = __shfl(xv, k);
        float4 w = rw[k * 64 + lane];
        r.x += xk * w.x; r.y += xk * w.y; r.z += xk * w.z; r.w += xk * w.w;
    }
    float4 cb = ((const float4*)conv_b)[lane];
    float v0 = a0 + cb.x + r.x, v1 = a1 + cb.y + r.y;
    float v2 = a2 + cb.z + r.z, v3 = a3 + cb.w + r.w;
    v0 = (v0 > 0.f) ? v0 : (__expf(v0) - 1.f);
    v1 = (v1 > 0.f) ? v1 : (__expf(v1) - 1.f);
    v2 = (v2 > 0.f) ? v2 : (__expf(v2) - 1.f);
    v3 = (v3 > 0.f) ? v3 : (__expf(v3) - 1.f);
    float mixed = 0.25f * (v0 + v1 + v2 + v3);   // lane-local head-mix

    float y = Y[n * 64 + lane];
    y  = y + (mixed - y - xv);    // DT=ALPHA=GAMMA=1
    xv = xv + y;
    Y[n * 64 + lane] = y;
    X[n * 64 + lane] = xv;
}

// ---------------- decoder: per-block partials (no global atomics) ----------------
__global__ void decoder_partial_kernel(const float* __restrict__ X, const float* __restrict__ dec_w,
                                       const float* __restrict__ dec_b, const int* __restrict__ batch,
                                       float* __restrict__ partials) {
    __shared__ float sg[N_GRAPHS];
    int t = threadIdx.x;                      // 256 threads = 4 waves
    if (t < N_GRAPHS) sg[t] = 0.f;
    __syncthreads();
    int lane = t & 63;
    int wave = t >> 6;
    const int npb = (N_NODES + DEC_BLOCKS - 1) / DEC_BLOCKS;   // 98
    int start = blockIdx.x * npb;
    int end   = min(start + npb, N_NODES);
    float dw = dec_w[lane];
    float db = dec_b[0];
    for (int n = start + wave; n < end; n += 4) {
        float p = X[n * 64 + lane] * dw;
        #pragma unroll
        for (int off = 32; off >= 1; off >>= 1) p += __shfl_down(p, off);
        if (lane == 0) atomicAdd(&sg[batch[n]], p + db);
    }
    __syncthreads();
    if (t < N_GRAPHS) partials[blockIdx.x * N_GRAPHS + t] = sg[t];
}

__global__ void decoder_reduce_kernel(const float* __restrict__ partials, float* __restrict__ out) {
    __shared__ float red[256];
    int t = threadIdx.x;
    int g = t & 63, j = t >> 6;
    float s = 0.f;
    for (int b = j * (DEC_BLOCKS / 4); b < (j + 1) * (DEC_BLOCKS / 4); ++b)
        s += partials[b * N_GRAPHS + g];
    red[t] = s;
    __syncthreads();
    if (t < 64) out[g] = red[g] + red[64 + g] + red[128 + g] + red[192 + g];
}

extern "C" void kernel_launch(void* const* d_in, const int* in_sizes, int n_in,
                              void* d_out, int out_size, void* d_ws, size_t ws_size,
                              hipStream_t stream) {
    const float* x       = (const float*)d_in[0];
    const float* pos     = (const float*)d_in[1];
    const int*   ei      = (const int*)d_in[2];
    const int*   batch   = (const int*)d_in[3];
    const float* enc_w   = (const float*)d_in[4];
    const float* enc_b   = (const float*)d_in[5];
    const float* res_w   = (const float*)d_in[6];
    const float* res_b   = (const float*)d_in[7];
    const float* lin_w   = (const float*)d_in[8];
    const float* att_src = (const float*)d_in[9];
    const float* att_dst = (const float*)d_in[10];
    const float* conv_b  = (const float*)d_in[11];
    const float* dec_w   = (const float*)d_in[12];
    const float* dec_b   = (const float*)d_in[13];
    float* out = (float*)d_out;

    char* ws = (char*)d_ws;
    size_t off = 0;
    auto alloc = [&](size_t bytes) -> void* {
        void* p = ws + off;
        off += (bytes + 255) & ~size_t(255);
        return p;
    };
    float* Y       = (float*)alloc((size_t)N_NODES * 64 * sizeof(float));
    float* X       = (float*)alloc((size_t)N_NODES * 64 * sizeof(float));
    __hip_bfloat16* h = (__hip_bfloat16*)alloc((size_t)N_NODES * HW * sizeof(__hip_bfloat16));
    float* a_src   = (float*)alloc((size_t)N_NODES * NHEADS * sizeof(float));
    float* a_dst   = (float*)alloc((size_t)N_NODES * NHEADS * sizeof(float));
    float* zbuf    = (float*)alloc((size_t)N_NODES * NHEADS * sizeof(float));
    float* att     = (float*)alloc((size_t)E_TOT * NHEADS * sizeof(float));
    float* partials= (float*)alloc((size_t)DEC_BLOCKS * N_GRAPHS * sizeof(float));
    int*   counts  = (int*)alloc((size_t)N_NODES * sizeof(int));
    int*   row_ptr = (int*)alloc((size_t)(N_NODES + 1) * sizeof(int));
    int*   cursor  = (int*)alloc((size_t)N_NODES * sizeof(int));
    int*   col     = (int*)alloc((size_t)E_TOT * sizeof(int));

    // ---- CSR build (dst is static; built each call for determinism) ----
    hipMemsetAsync(counts, 0, (size_t)N_NODES * sizeof(int), stream);
    const int eb = (E_TOT + 255) / 256;
    hist_kernel<<<eb, 256, 0, stream>>>(ei, counts);
    scan_kernel<<<1, 1024, 0, stream>>>(counts, row_ptr);
    hipMemcpyAsync(cursor, row_ptr, (size_t)N_NODES * sizeof(int),
                   hipMemcpyDeviceToDevice, stream);
    scatter_kernel<<<eb, 256, 0, stream>>>(ei, cursor, col);

    encoder_kernel<<<N_NODES, 64, 0, stream>>>(x, pos, enc_w, enc_b, Y, X);

    const int ab = (N_NODES * 64 + 255) / 256;   // one wave per node
    for (int layer = 0; layer < 3; ++layer) {
        lin_kernel<<<N_NODES, 256, 0, stream>>>(X, lin_w, att_src, att_dst, h, a_src, a_dst);
        attn_kernel<<<ab, 256, 0, stream>>>(row_ptr, col, a_src, a_dst, att, zbuf);
        msg_combine_kernel<<<ab, 256, 0, stream>>>(row_ptr, col, att, zbuf, h,
                                                   conv_b, res_w, res_b, Y, X);
    }

    decoder_partial_kernel<<<DEC_BLOCKS, 256, 0, stream>>>(X, dec_w, dec_b, batch, partials);
    decoder_reduce_kernel<<<1, 256, 0, stream>>>(partials, out);
}

// Round 6
// 1090.358 us; speedup vs baseline: 3.1859x; 1.0307x over previous
//
#include <hip/hip_runtime.h>
#include <hip/hip_bf16.h>

#define N_NODES  50000
#define N_EDGES  800000
#define E_TOT    850000   // edges + self loops
#define N_GRAPHS 64
#define NHID     64
#define NHEADS   4
#define HW       256      // NHEADS*NHID
#define NEG_SLOPE 0.2f
#define DEC_BLOCKS 512

__device__ __forceinline__ float bf2f(unsigned short u) {
    return __uint_as_float(((unsigned)u) << 16);
}
__device__ __forceinline__ float lrelu(float v) {
    return (v > 0.f) ? v : NEG_SLOPE * v;
}

// ---------------- encoder: Y = X = [x|pos] @ enc_w + enc_b ----------------
__global__ void encoder_kernel(const float* __restrict__ x, const float* __restrict__ pos,
                               const float* __restrict__ enc_w, const float* __restrict__ enc_b,
                               float* __restrict__ Y, float* __restrict__ X) {
    int n = blockIdx.x;
    int c = threadIdx.x;            // 0..63
    __shared__ float row[128];
    for (int k = c; k < 128; k += 64)
        row[k] = (k < 125) ? x[n * 125 + k] : pos[n * 3 + (k - 125)];
    __syncthreads();
    float acc = enc_b[c];
    #pragma unroll 8
    for (int k = 0; k < 128; ++k) acc += row[k] * enc_w[k * 64 + c];
    Y[n * 64 + c] = acc;
    X[n * 64 + c] = acc;
}

// ---------------- CSR build ----------------
__global__ void hist_kernel(const int* __restrict__ ei, int* __restrict__ counts) {
    int e = blockIdx.x * blockDim.x + threadIdx.x;
    if (e >= E_TOT) return;
    int d = (e < N_EDGES) ? ei[N_EDGES + e] : (e - N_EDGES);
    atomicAdd(&counts[d], 1);
}

__global__ void scan_kernel(const int* __restrict__ counts, int* __restrict__ row_ptr,
                            int* __restrict__ cursor) {
    __shared__ int part[1024];
    int t = threadIdx.x;
    const int chunk = (N_NODES + 1023) / 1024;   // 49
    int base = t * chunk;
    int sum = 0;
    for (int i = 0; i < chunk; ++i) {
        int idx = base + i;
        if (idx < N_NODES) sum += counts[idx];
    }
    part[t] = sum;
    __syncthreads();
    for (int off = 1; off < 1024; off <<= 1) {
        int v = (t >= off) ? part[t - off] : 0;
        __syncthreads();
        part[t] += v;
        __syncthreads();
    }
    int run = (t == 0) ? 0 : part[t - 1];
    for (int i = 0; i < chunk; ++i) {
        int idx = base + i;
        if (idx < N_NODES) { row_ptr[idx] = run; cursor[idx] = run; run += counts[idx]; }
    }
    if (t == 1023) row_ptr[N_NODES] = part[1023];
}

__global__ void scatter_kernel(const int* __restrict__ ei, int* __restrict__ cursor,
                               int* __restrict__ col) {
    int e = blockIdx.x * blockDim.x + threadIdx.x;
    if (e >= E_TOT) return;
    int s, d;
    if (e < N_EDGES) { s = ei[e]; d = ei[N_EDGES + e]; }
    else             { s = d = e - N_EDGES; }
    int pos = atomicAdd(&cursor[d], 1);
    col[pos] = s;
}

// ---------------- h = X @ lin_w (bf16 out); a_src/a_dst per head ----------------
__global__ void lin_kernel(const float* __restrict__ X, const float* __restrict__ lin_w,
                           const float* __restrict__ att_src, const float* __restrict__ att_dst,
                           __hip_bfloat16* __restrict__ h, float* __restrict__ a_src,
                           float* __restrict__ a_dst) {
    int n = blockIdx.x;
    int t = threadIdx.x;            // 0..255
    __shared__ float xrow[64];
    if (t < 64) xrow[t] = X[n * 64 + t];
    __syncthreads();
    float acc = 0.f;
    #pragma unroll 8
    for (int k = 0; k < 64; ++k) acc += xrow[k] * lin_w[k * 256 + t];
    h[n * 256 + t] = __float2bfloat16(acc);   // logits below use fp32 acc (pre-rounding)
    int head = t >> 6, c = t & 63;  // each wave (64 lanes) == one head
    float ps = acc * att_src[head * 64 + c];
    float pd = acc * att_dst[head * 64 + c];
    for (int off = 32; off >= 1; off >>= 1) {
        ps += __shfl_down(ps, off);
        pd += __shfl_down(pd, off);
    }
    if (c == 0) { a_src[n * 4 + head] = ps; a_dst[n * 4 + head] = pd; }
}

// ---- FUSED: attention softmax + gather + residual + elu + head-mix + GraphCON update ----
// one wave per dst node; lane owns 4 output channels (all in head = lane>>4)
__global__ void fused_gat_kernel(const int* __restrict__ rp, const int* __restrict__ col,
                                 const float* __restrict__ a_src, const float* __restrict__ a_dst,
                                 const __hip_bfloat16* __restrict__ h,
                                 const float* __restrict__ conv_b,
                                 const float* __restrict__ res_w, const float* __restrict__ res_b,
                                 float* __restrict__ Y, float* __restrict__ X) {
    int n = (blockIdx.x * blockDim.x + threadIdx.x) >> 6;
    if (n >= N_NODES) return;
    int lane = threadIdx.x & 63;
    int head = lane >> 4;
    int base = rp[n];
    int deg  = rp[n + 1] - base;
    const ushort* hp = (const ushort*)h;
    float4 ad = ((const float4*)a_dst)[n];

    float a0 = 0.f, a1 = 0.f, a2 = 0.f, a3 = 0.f;

    if (deg <= 64) {
        // ---- phase A: lane j owns edge j; logits for all 4 heads in registers ----
        int s = 0;
        float l0 = -3.0e38f, l1 = -3.0e38f, l2 = -3.0e38f, l3 = -3.0e38f;
        if (lane < deg) {
            s = col[base + lane];                       // coalesced
            float4 as = ((const float4*)a_src)[s];      // one 16B gather per edge
            l0 = lrelu(as.x + ad.x); l1 = lrelu(as.y + ad.y);
            l2 = lrelu(as.z + ad.z); l3 = lrelu(as.w + ad.w);
        }
        float m0 = l0, m1 = l1, m2 = l2, m3 = l3;
        #pragma unroll
        for (int off = 1; off < 64; off <<= 1) {
            m0 = fmaxf(m0, __shfl_xor(m0, off)); m1 = fmaxf(m1, __shfl_xor(m1, off));
            m2 = fmaxf(m2, __shfl_xor(m2, off)); m3 = fmaxf(m3, __shfl_xor(m3, off));
        }
        float e0 = (lane < deg) ? __expf(l0 - m0) : 0.f;
        float e1 = (lane < deg) ? __expf(l1 - m1) : 0.f;
        float e2 = (lane < deg) ? __expf(l2 - m2) : 0.f;
        float e3 = (lane < deg) ? __expf(l3 - m3) : 0.f;
        float z0 = e0, z1 = e1, z2 = e2, z3 = e3;
        #pragma unroll
        for (int off = 1; off < 64; off <<= 1) {
            z0 += __shfl_xor(z0, off); z1 += __shfl_xor(z1, off);
            z2 += __shfl_xor(z2, off); z3 += __shfl_xor(z3, off);
        }
        e0 /= z0; e1 /= z1; e2 /= z2; e3 /= z3;   // lane j holds normalized att of edge j

        // ---- phase B: per-edge weight + src id via shfl (no memory) ----
        for (int j = 0; j < deg; ++j) {
            int   sj = __shfl(s, j);
            float w0 = __shfl(e0, j), w1 = __shfl(e1, j);
            float w2 = __shfl(e2, j), w3 = __shfl(e3, j);
            float w  = (head == 0) ? w0 : (head == 1) ? w1 : (head == 2) ? w2 : w3;
            ushort4 v = *(const ushort4*)(hp + (size_t)sj * 256 + lane * 4);
            a0 += w * bf2f(v.x); a1 += w * bf2f(v.y);
            a2 += w * bf2f(v.z); a3 += w * bf2f(v.w);
        }
    } else {
        // ---- rare fallback (deg > 64): chunked online softmax, then weighted gather ----
        float m0 = -3.0e38f, m1 = -3.0e38f, m2 = -3.0e38f, m3 = -3.0e38f;
        float z0 = 0.f, z1 = 0.f, z2 = 0.f, z3 = 0.f;
        for (int c0 = 0; c0 < deg; c0 += 64) {
            int j = c0 + lane;
            float l0 = -3.0e38f, l1 = -3.0e38f, l2 = -3.0e38f, l3 = -3.0e38f;
            if (j < deg) {
                int s = col[base + j];
                float4 as = ((const float4*)a_src)[s];
                l0 = lrelu(as.x + ad.x); l1 = lrelu(as.y + ad.y);
                l2 = lrelu(as.z + ad.z); l3 = lrelu(as.w + ad.w);
            }
            float c0m = l0, c1m = l1, c2m = l2, c3m = l3;
            #pragma unroll
            for (int off = 1; off < 64; off <<= 1) {
                c0m = fmaxf(c0m, __shfl_xor(c0m, off)); c1m = fmaxf(c1m, __shfl_xor(c1m, off));
                c2m = fmaxf(c2m, __shfl_xor(c2m, off)); c3m = fmaxf(c3m, __shfl_xor(c3m, off));
            }
            float n0 = fmaxf(m0, c0m), n1 = fmaxf(m1, c1m);
            float n2 = fmaxf(m2, c2m), n3 = fmaxf(m3, c3m);
            z0 *= __expf(m0 - n0); z1 *= __expf(m1 - n1);
            z2 *= __expf(m2 - n2); z3 *= __expf(m3 - n3);
            m0 = n0; m1 = n1; m2 = n2; m3 = n3;
            float e0 = (j < deg) ? __expf(l0 - m0) : 0.f;
            float e1 = (j < deg) ? __expf(l1 - m1) : 0.f;
            float e2 = (j < deg) ? __expf(l2 - m2) : 0.f;
            float e3 = (j < deg) ? __expf(l3 - m3) : 0.f;
            #pragma unroll
            for (int off = 1; off < 64; off <<= 1) {
                e0 += __shfl_xor(e0, off); e1 += __shfl_xor(e1, off);
                e2 += __shfl_xor(e2, off); e3 += __shfl_xor(e3, off);
            }
            z0 += e0; z1 += e1; z2 += e2; z3 += e3;
        }
        for (int c0 = 0; c0 < deg; c0 += 64) {
            int j = c0 + lane;
            int s = 0;
            float e0 = 0.f, e1 = 0.f, e2 = 0.f, e3 = 0.f;
            if (j < deg) {
                s = col[base + j];
                float4 as = ((const float4*)a_src)[s];
                e0 = __expf(lrelu(as.x + ad.x) - m0) / z0;
                e1 = __expf(lrelu(as.y + ad.y) - m1) / z1;
                e2 = __expf(lrelu(as.z + ad.z) - m2) / z2;
                e3 = __expf(lrelu(as.w + ad.w) - m3) / z3;
            }
            int cnt = min(64, deg - c0);
            for (int jj = 0; jj < cnt; ++jj) {
                int   sj = __shfl(s, jj);
                float w0 = __shfl(e0, jj), w1 = __shfl(e1, jj);
                float w2 = __shfl(e2, jj), w3 = __shfl(e3, jj);
                float w  = (head == 0) ? w0 : (head == 1) ? w1 : (head == 2) ? w2 : w3;
                ushort4 v = *(const ushort4*)(hp + (size_t)sj * 256 + lane * 4);
                a0 += w * bf2f(v.x); a1 += w * bf2f(v.y);
                a2 += w * bf2f(v.z); a3 += w * bf2f(v.w);
            }
        }
    }

    // ---- residual GEMV (lane's 4 channels), elu, lane-local head-mix, update ----
    float xv = X[n * 64 + lane];
    float4 r = ((const float4*)res_b)[lane];
    const float4* rw = (const float4*)res_w;
    #pragma unroll 8
    for (int k = 0; k < 64; ++k) {
        float xk = __shfl(xv, k);
        float4 w = rw[k * 64 + lane];
        r.x += xk * w.x; r.y += xk * w.y; r.z += xk * w.z; r.w += xk * w.w;
    }
    float4 cb = ((const float4*)conv_b)[lane];
    float v0 = a0 + cb.x + r.x, v1 = a1 + cb.y + r.y;
    float v2 = a2 + cb.z + r.z, v3 = a3 + cb.w + r.w;
    v0 = (v0 > 0.f) ? v0 : (__expf(v0) - 1.f);
    v1 = (v1 > 0.f) ? v1 : (__expf(v1) - 1.f);
    v2 = (v2 > 0.f) ? v2 : (__expf(v2) - 1.f);
    v3 = (v3 > 0.f) ? v3 : (__expf(v3) - 1.f);
    float mixed = 0.25f * (v0 + v1 + v2 + v3);

    float y = Y[n * 64 + lane];
    y  = y + (mixed - y - xv);    // DT=ALPHA=GAMMA=1
    xv = xv + y;
    Y[n * 64 + lane] = y;
    X[n * 64 + lane] = xv;
}

// ---------------- decoder: per-block partials (no global atomics) ----------------
__global__ void decoder_partial_kernel(const float* __restrict__ X, const float* __restrict__ dec_w,
                                       const float* __restrict__ dec_b, const int* __restrict__ batch,
                                       float* __restrict__ partials) {
    __shared__ float sg[N_GRAPHS];
    int t = threadIdx.x;                      // 256 threads = 4 waves
    if (t < N_GRAPHS) sg[t] = 0.f;
    __syncthreads();
    int lane = t & 63;
    int wave = t >> 6;
    const int npb = (N_NODES + DEC_BLOCKS - 1) / DEC_BLOCKS;   // 98
    int start = blockIdx.x * npb;
    int end   = min(start + npb, N_NODES);
    float dw = dec_w[lane];
    float db = dec_b[0];
    for (int n = start + wave; n < end; n += 4) {
        float p = X[n * 64 + lane] * dw;
        #pragma unroll
        for (int off = 32; off >= 1; off >>= 1) p += __shfl_down(p, off);
        if (lane == 0) atomicAdd(&sg[batch[n]], p + db);
    }
    __syncthreads();
    if (t < N_GRAPHS) partials[blockIdx.x * N_GRAPHS + t] = sg[t];
}

__global__ void decoder_reduce_kernel(const float* __restrict__ partials, float* __restrict__ out) {
    __shared__ float red[256];
    int t = threadIdx.x;
    int g = t & 63, j = t >> 6;
    float s = 0.f;
    for (int b = j * (DEC_BLOCKS / 4); b < (j + 1) * (DEC_BLOCKS / 4); ++b)
        s += partials[b * N_GRAPHS + g];
    red[t] = s;
    __syncthreads();
    if (t < 64) out[g] = red[g] + red[64 + g] + red[128 + g] + red[192 + g];
}

extern "C" void kernel_launch(void* const* d_in, const int* in_sizes, int n_in,
                              void* d_out, int out_size, void* d_ws, size_t ws_size,
                              hipStream_t stream) {
    const float* x       = (const float*)d_in[0];
    const float* pos     = (const float*)d_in[1];
    const int*   ei      = (const int*)d_in[2];
    const int*   batch   = (const int*)d_in[3];
    const float* enc_w   = (const float*)d_in[4];
    const float* enc_b   = (const float*)d_in[5];
    const float* res_w   = (const float*)d_in[6];
    const float* res_b   = (const float*)d_in[7];
    const float* lin_w   = (const float*)d_in[8];
    const float* att_src = (const float*)d_in[9];
    const float* att_dst = (const float*)d_in[10];
    const float* conv_b  = (const float*)d_in[11];
    const float* dec_w   = (const float*)d_in[12];
    const float* dec_b   = (const float*)d_in[13];
    float* out = (float*)d_out;

    char* ws = (char*)d_ws;
    size_t off = 0;
    auto alloc = [&](size_t bytes) -> void* {
        void* p = ws + off;
        off += (bytes + 255) & ~size_t(255);
        return p;
    };
    float* Y       = (float*)alloc((size_t)N_NODES * 64 * sizeof(float));
    float* X       = (float*)alloc((size_t)N_NODES * 64 * sizeof(float));
    __hip_bfloat16* h = (__hip_bfloat16*)alloc((size_t)N_NODES * HW * sizeof(__hip_bfloat16));
    float* a_src   = (float*)alloc((size_t)N_NODES * NHEADS * sizeof(float));
    float* a_dst   = (float*)alloc((size_t)N_NODES * NHEADS * sizeof(float));
    float* partials= (float*)alloc((size_t)DEC_BLOCKS * N_GRAPHS * sizeof(float));
    int*   counts  = (int*)alloc((size_t)N_NODES * sizeof(int));
    int*   row_ptr = (int*)alloc((size_t)(N_NODES + 1) * sizeof(int));
    int*   cursor  = (int*)alloc((size_t)N_NODES * sizeof(int));
    int*   col     = (int*)alloc((size_t)E_TOT * sizeof(int));

    // ---- CSR build (dst is static; built each call for determinism) ----
    hipMemsetAsync(counts, 0, (size_t)N_NODES * sizeof(int), stream);
    const int eb = (E_TOT + 255) / 256;
    hist_kernel<<<eb, 256, 0, stream>>>(ei, counts);
    scan_kernel<<<1, 1024, 0, stream>>>(counts, row_ptr, cursor);
    scatter_kernel<<<eb, 256, 0, stream>>>(ei, cursor, col);

    encoder_kernel<<<N_NODES, 64, 0, stream>>>(x, pos, enc_w, enc_b, Y, X);

    const int ab = (N_NODES * 64 + 255) / 256;   // one wave per node
    for (int layer = 0; layer < 3; ++layer) {
        lin_kernel<<<N_NODES, 256, 0, stream>>>(X, lin_w, att_src, att_dst, h, a_src, a_dst);
        fused_gat_kernel<<<ab, 256, 0, stream>>>(row_ptr, col, a_src, a_dst, h,
                                                 conv_b, res_w, res_b, Y, X);
    }

    decoder_partial_kernel<<<DEC_BLOCKS, 256, 0, stream>>>(X, dec_w, dec_b, batch, partials);
    decoder_reduce_kernel<<<1, 256, 0, stream>>>(partials, out);
}

// Round 7
// 951.450 us; speedup vs baseline: 3.6510x; 1.1460x over previous
//
#include <hip/hip_runtime.h>
#include <hip/hip_bf16.h>

#define N_NODES  50000
#define N_EDGES  800000
#define E_TOT    850000   // edges + self loops
#define N_GRAPHS 64
#define NHID     64
#define NHEADS   4
#define HW       256      // NHEADS*NHID
#define NEG_SLOPE 0.2f
#define DEC_BLOCKS 512
#define LIN_NPB  16
#define ENC_NPB  32

__device__ __forceinline__ float bf2f(unsigned short u) {
    return __uint_as_float(((unsigned)u) << 16);
}
__device__ __forceinline__ float lrelu(float v) {
    return (v > 0.f) ? v : NEG_SLOPE * v;
}

// ---------------- encoder: Y = X = [x|pos] @ enc_w + enc_b (32 nodes/block) ----------------
__global__ __launch_bounds__(256) void encoder_kernel(
        const float* __restrict__ x, const float* __restrict__ pos,
        const float* __restrict__ enc_w, const float* __restrict__ enc_b,
        float* __restrict__ Y, float* __restrict__ X) {
    __shared__ float ws[128 * 64];       // 32 KB: whole enc_w
    __shared__ float xs[ENC_NPB][128];   // 16 KB: staged input rows
    int t = threadIdx.x;
    int base = blockIdx.x * ENC_NPB;
    int nx = min(ENC_NPB, N_NODES - base);
    for (int i = t; i < 128 * 64; i += 256) ws[i] = enc_w[i];
    for (int i = t; i < nx * 125; i += 256) {        // x rows are contiguous: coalesced
        int nn = i / 125, k = i - nn * 125;
        xs[nn][k] = x[(size_t)base * 125 + i];
    }
    for (int i = t; i < nx * 3; i += 256) {
        int nn = i / 3, k = i - nn * 3;
        xs[nn][125 + k] = pos[(size_t)(base + nn) * 3 + k];
    }
    __syncthreads();
    int c = t & 63, wv = t >> 6;
    float bias = enc_b[c];
    for (int nn = wv; nn < nx; nn += 4) {
        float acc = bias;
        #pragma unroll 16
        for (int k = 0; k < 128; ++k) acc += xs[nn][k] * ws[k * 64 + c];
        int n = base + nn;
        Y[n * 64 + c] = acc;
        X[n * 64 + c] = acc;
    }
}

// ---------------- CSR build ----------------
__global__ void hist_kernel(const int* __restrict__ ei, int* __restrict__ counts) {
    int e = blockIdx.x * blockDim.x + threadIdx.x;
    if (e >= E_TOT) return;
    int d = (e < N_EDGES) ? ei[N_EDGES + e] : (e - N_EDGES);
    atomicAdd(&counts[d], 1);
}

__global__ void scan_kernel(const int* __restrict__ counts, int* __restrict__ row_ptr,
                            int* __restrict__ cursor) {
    __shared__ int part[1024];
    int t = threadIdx.x;
    const int chunk = (N_NODES + 1023) / 1024;   // 49
    int base = t * chunk;
    int sum = 0;
    for (int i = 0; i < chunk; ++i) {
        int idx = base + i;
        if (idx < N_NODES) sum += counts[idx];
    }
    part[t] = sum;
    __syncthreads();
    for (int off = 1; off < 1024; off <<= 1) {
        int v = (t >= off) ? part[t - off] : 0;
        __syncthreads();
        part[t] += v;
        __syncthreads();
    }
    int run = (t == 0) ? 0 : part[t - 1];
    for (int i = 0; i < chunk; ++i) {
        int idx = base + i;
        if (idx < N_NODES) { row_ptr[idx] = run; cursor[idx] = run; run += counts[idx]; }
    }
    if (t == 1023) row_ptr[N_NODES] = part[1023];
}

__global__ void scatter_kernel(const int* __restrict__ ei, int* __restrict__ cursor,
                               int* __restrict__ col) {
    int e = blockIdx.x * blockDim.x + threadIdx.x;
    if (e >= E_TOT) return;
    int s, d;
    if (e < N_EDGES) { s = ei[e]; d = ei[N_EDGES + e]; }
    else             { s = d = e - N_EDGES; }
    int pos = atomicAdd(&cursor[d], 1);
    col[pos] = s;
}

// ------- h = X @ lin_w (bf16 out); a_src/a_dst per head; 16 nodes/block, weights in regs -------
__global__ __launch_bounds__(256) void lin_kernel(
        const float* __restrict__ X, const float* __restrict__ lin_w,
        const float* __restrict__ att_src, const float* __restrict__ att_dst,
        __hip_bfloat16* __restrict__ h, float* __restrict__ a_src,
        float* __restrict__ a_dst) {
    int t = threadIdx.x;            // 0..255; flat output channel
    int head = t >> 6, c = t & 63;
    int base = blockIdx.x * LIN_NPB;
    float wcol[64];                 // this thread's lin_w column
    #pragma unroll
    for (int k = 0; k < 64; ++k) wcol[k] = lin_w[k * 256 + t];
    __shared__ float xs[LIN_NPB][64];
    for (int i = t; i < LIN_NPB * 64; i += 256) {
        int n = base + (i >> 6);
        if (n < N_NODES) xs[i >> 6][i & 63] = X[n * 64 + (i & 63)];
    }
    __syncthreads();
    float asv = att_src[head * 64 + c];
    float adv = att_dst[head * 64 + c];
    int nx = min(LIN_NPB, N_NODES - base);
    for (int nn = 0; nn < nx; ++nn) {
        float acc = 0.f;
        #pragma unroll
        for (int k = 0; k < 64; ++k) acc += xs[nn][k] * wcol[k];
        int n = base + nn;
        h[n * 256 + t] = __float2bfloat16(acc);   // logits use fp32 acc (pre-rounding)
        float ps = acc * asv;
        float pd = acc * adv;
        #pragma unroll
        for (int off = 32; off >= 1; off >>= 1) {
            ps += __shfl_down(ps, off);
            pd += __shfl_down(pd, off);
        }
        if (c == 0) { a_src[n * 4 + head] = ps; a_dst[n * 4 + head] = pd; }
    }
}

// ---- FUSED: attention softmax + gather + residual + elu + head-mix + GraphCON update ----
// one wave per dst node; lane owns 4 output channels (all in head = lane>>4)
__global__ void fused_gat_kernel(const int* __restrict__ rp, const int* __restrict__ col,
                                 const float* __restrict__ a_src, const float* __restrict__ a_dst,
                                 const __hip_bfloat16* __restrict__ h,
                                 const float* __restrict__ conv_b,
                                 const float* __restrict__ res_w, const float* __restrict__ res_b,
                                 float* __restrict__ Y, float* __restrict__ X) {
    int n = (blockIdx.x * blockDim.x + threadIdx.x) >> 6;
    if (n >= N_NODES) return;
    int lane = threadIdx.x & 63;
    int head = lane >> 4;
    int base = rp[n];
    int deg  = rp[n + 1] - base;
    const ushort* hp = (const ushort*)h;
    float4 ad = ((const float4*)a_dst)[n];

    float a0 = 0.f, a1 = 0.f, a2 = 0.f, a3 = 0.f;

    if (deg <= 64) {
        int s = 0;
        float l0 = -3.0e38f, l1 = -3.0e38f, l2 = -3.0e38f, l3 = -3.0e38f;
        if (lane < deg) {
            s = col[base + lane];                       // coalesced
            float4 as = ((const float4*)a_src)[s];      // one 16B gather per edge
            l0 = lrelu(as.x + ad.x); l1 = lrelu(as.y + ad.y);
            l2 = lrelu(as.z + ad.z); l3 = lrelu(as.w + ad.w);
        }
        float m0 = l0, m1 = l1, m2 = l2, m3 = l3;
        #pragma unroll
        for (int off = 1; off < 64; off <<= 1) {
            m0 = fmaxf(m0, __shfl_xor(m0, off)); m1 = fmaxf(m1, __shfl_xor(m1, off));
            m2 = fmaxf(m2, __shfl_xor(m2, off)); m3 = fmaxf(m3, __shfl_xor(m3, off));
        }
        float e0 = (lane < deg) ? __expf(l0 - m0) : 0.f;
        float e1 = (lane < deg) ? __expf(l1 - m1) : 0.f;
        float e2 = (lane < deg) ? __expf(l2 - m2) : 0.f;
        float e3 = (lane < deg) ? __expf(l3 - m3) : 0.f;
        float z0 = e0, z1 = e1, z2 = e2, z3 = e3;
        #pragma unroll
        for (int off = 1; off < 64; off <<= 1) {
            z0 += __shfl_xor(z0, off); z1 += __shfl_xor(z1, off);
            z2 += __shfl_xor(z2, off); z3 += __shfl_xor(z3, off);
        }
        e0 /= z0; e1 /= z1; e2 /= z2; e3 /= z3;

        for (int j = 0; j < deg; ++j) {
            int   sj = __shfl(s, j);
            float w0 = __shfl(e0, j), w1 = __shfl(e1, j);
            float w2 = __shfl(e2, j), w3 = __shfl(e3, j);
            float w  = (head == 0) ? w0 : (head == 1) ? w1 : (head == 2) ? w2 : w3;
            ushort4 v = *(const ushort4*)(hp + (size_t)sj * 256 + lane * 4);
            a0 += w * bf2f(v.x); a1 += w * bf2f(v.y);
            a2 += w * bf2f(v.z); a3 += w * bf2f(v.w);
        }
    } else {
        float m0 = -3.0e38f, m1 = -3.0e38f, m2 = -3.0e38f, m3 = -3.0e38f;
        float z0 = 0.f, z1 = 0.f, z2 = 0.f, z3 = 0.f;
        for (int c0 = 0; c0 < deg; c0 += 64) {
            int j = c0 + lane;
            float l0 = -3.0e38f, l1 = -3.0e38f, l2 = -3.0e38f, l3 = -3.0e38f;
            if (j < deg) {
                int s = col[base + j];
                float4 as = ((const float4*)a_src)[s];
                l0 = lrelu(as.x + ad.x); l1 = lrelu(as.y + ad.y);
                l2 = lrelu(as.z + ad.z); l3 = lrelu(as.w + ad.w);
            }
            float c0m = l0, c1m = l1, c2m = l2, c3m = l3;
            #pragma unroll
            for (int off = 1; off < 64; off <<= 1) {
                c0m = fmaxf(c0m, __shfl_xor(c0m, off)); c1m = fmaxf(c1m, __shfl_xor(c1m, off));
                c2m = fmaxf(c2m, __shfl_xor(c2m, off)); c3m = fmaxf(c3m, __shfl_xor(c3m, off));
            }
            float n0 = fmaxf(m0, c0m), n1 = fmaxf(m1, c1m);
            float n2 = fmaxf(m2, c2m), n3 = fmaxf(m3, c3m);
            z0 *= __expf(m0 - n0); z1 *= __expf(m1 - n1);
            z2 *= __expf(m2 - n2); z3 *= __expf(m3 - n3);
            m0 = n0; m1 = n1; m2 = n2; m3 = n3;
            float e0 = (j < deg) ? __expf(l0 - m0) : 0.f;
            float e1 = (j < deg) ? __expf(l1 - m1) : 0.f;
            float e2 = (j < deg) ? __expf(l2 - m2) : 0.f;
            float e3 = (j < deg) ? __expf(l3 - m3) : 0.f;
            #pragma unroll
            for (int off = 1; off < 64; off <<= 1) {
                e0 += __shfl_xor(e0, off); e1 += __shfl_xor(e1, off);
                e2 += __shfl_xor(e2, off); e3 += __shfl_xor(e3, off);
            }
            z0 += e0; z1 += e1; z2 += e2; z3 += e3;
        }
        for (int c0 = 0; c0 < deg; c0 += 64) {
            int j = c0 + lane;
            int s = 0;
            float e0 = 0.f, e1 = 0.f, e2 = 0.f, e3 = 0.f;
            if (j < deg) {
                s = col[base + j];
                float4 as = ((const float4*)a_src)[s];
                e0 = __expf(lrelu(as.x + ad.x) - m0) / z0;
                e1 = __expf(lrelu(as.y + ad.y) - m1) / z1;
                e2 = __expf(lrelu(as.z + ad.z) - m2) / z2;
                e3 = __expf(lrelu(as.w + ad.w) - m3) / z3;
            }
            int cnt = min(64, deg - c0);
            for (int jj = 0; jj < cnt; ++jj) {
                int   sj = __shfl(s, jj);
                float w0 = __shfl(e0, jj), w1 = __shfl(e1, jj);
                float w2 = __shfl(e2, jj), w3 = __shfl(e3, jj);
                float w  = (head == 0) ? w0 : (head == 1) ? w1 : (head == 2) ? w2 : w3;
                ushort4 v = *(const ushort4*)(hp + (size_t)sj * 256 + lane * 4);
                a0 += w * bf2f(v.x); a1 += w * bf2f(v.y);
                a2 += w * bf2f(v.z); a3 += w * bf2f(v.w);
            }
        }
    }

    // ---- residual GEMV (lane's 4 channels), elu, lane-local head-mix, update ----
    float xv = X[n * 64 + lane];
    float4 r = ((const float4*)res_b)[lane];
    const float4* rw = (const float4*)res_w;
    #pragma unroll 8
    for (int k = 0; k < 64; ++k) {
        float xk = __shfl(xv, k);
        float4 w = rw[k * 64 + lane];
        r.x += xk * w.x; r.y += xk * w.y; r.z += xk * w.z; r.w += xk * w.w;
    }
    float4 cb = ((const float4*)conv_b)[lane];
    float v0 = a0 + cb.x + r.x, v1 = a1 + cb.y + r.y;
    float v2 = a2 + cb.z + r.z, v3 = a3 + cb.w + r.w;
    v0 = (v0 > 0.f) ? v0 : (__expf(v0) - 1.f);
    v1 = (v1 > 0.f) ? v1 : (__expf(v1) - 1.f);
    v2 = (v2 > 0.f) ? v2 : (__expf(v2) - 1.f);
    v3 = (v3 > 0.f) ? v3 : (__expf(v3) - 1.f);
    float mixed = 0.25f * (v0 + v1 + v2 + v3);

    float y = Y[n * 64 + lane];
    y  = y + (mixed - y - xv);    // DT=ALPHA=GAMMA=1
    xv = xv + y;
    Y[n * 64 + lane] = y;
    X[n * 64 + lane] = xv;
}

// ---------------- decoder: per-block partials (no global atomics) ----------------
__global__ void decoder_partial_kernel(const float* __restrict__ X, const float* __restrict__ dec_w,
                                       const float* __restrict__ dec_b, const int* __restrict__ batch,
                                       float* __restrict__ partials) {
    __shared__ float sg[N_GRAPHS];
    int t = threadIdx.x;                      // 256 threads = 4 waves
    if (t < N_GRAPHS) sg[t] = 0.f;
    __syncthreads();
    int lane = t & 63;
    int wave = t >> 6;
    const int npb = (N_NODES + DEC_BLOCKS - 1) / DEC_BLOCKS;   // 98
    int start = blockIdx.x * npb;
    int end   = min(start + npb, N_NODES);
    float dw = dec_w[lane];
    float db = dec_b[0];
    for (int n = start + wave; n < end; n += 4) {
        float p = X[n * 64 + lane] * dw;
        #pragma unroll
        for (int off = 32; off >= 1; off >>= 1) p += __shfl_down(p, off);
        if (lane == 0) atomicAdd(&sg[batch[n]], p + db);
    }
    __syncthreads();
    if (t < N_GRAPHS) partials[blockIdx.x * N_GRAPHS + t] = sg[t];
}

__global__ void decoder_reduce_kernel(const float* __restrict__ partials, float* __restrict__ out) {
    __shared__ float red[256];
    int t = threadIdx.x;
    int g = t & 63, j = t >> 6;
    float s = 0.f;
    for (int b = j * (DEC_BLOCKS / 4); b < (j + 1) * (DEC_BLOCKS / 4); ++b)
        s += partials[b * N_GRAPHS + g];
    red[t] = s;
    __syncthreads();
    if (t < 64) out[g] = red[g] + red[64 + g] + red[128 + g] + red[192 + g];
}

extern "C" void kernel_launch(void* const* d_in, const int* in_sizes, int n_in,
                              void* d_out, int out_size, void* d_ws, size_t ws_size,
                              hipStream_t stream) {
    const float* x       = (const float*)d_in[0];
    const float* pos     = (const float*)d_in[1];
    const int*   ei      = (const int*)d_in[2];
    const int*   batch   = (const int*)d_in[3];
    const float* enc_w   = (const float*)d_in[4];
    const float* enc_b   = (const float*)d_in[5];
    const float* res_w   = (const float*)d_in[6];
    const float* res_b   = (const float*)d_in[7];
    const float* lin_w   = (const float*)d_in[8];
    const float* att_src = (const float*)d_in[9];
    const float* att_dst = (const float*)d_in[10];
    const float* conv_b  = (const float*)d_in[11];
    const float* dec_w   = (const float*)d_in[12];
    const float* dec_b   = (const float*)d_in[13];
    float* out = (float*)d_out;

    char* ws = (char*)d_ws;
    size_t off = 0;
    auto alloc = [&](size_t bytes) -> void* {
        void* p = ws + off;
        off += (bytes + 255) & ~size_t(255);
        return p;
    };
    float* Y       = (float*)alloc((size_t)N_NODES * 64 * sizeof(float));
    float* X       = (float*)alloc((size_t)N_NODES * 64 * sizeof(float));
    __hip_bfloat16* h = (__hip_bfloat16*)alloc((size_t)N_NODES * HW * sizeof(__hip_bfloat16));
    float* a_src   = (float*)alloc((size_t)N_NODES * NHEADS * sizeof(float));
    float* a_dst   = (float*)alloc((size_t)N_NODES * NHEADS * sizeof(float));
    float* partials= (float*)alloc((size_t)DEC_BLOCKS * N_GRAPHS * sizeof(float));
    int*   counts  = (int*)alloc((size_t)N_NODES * sizeof(int));
    int*   row_ptr = (int*)alloc((size_t)(N_NODES + 1) * sizeof(int));
    int*   cursor  = (int*)alloc((size_t)N_NODES * sizeof(int));
    int*   col     = (int*)alloc((size_t)E_TOT * sizeof(int));

    // ---- CSR build (dst is static; built each call for determinism) ----
    hipMemsetAsync(counts, 0, (size_t)N_NODES * sizeof(int), stream);
    const int eb = (E_TOT + 255) / 256;
    hist_kernel<<<eb, 256, 0, stream>>>(ei, counts);
    scan_kernel<<<1, 1024, 0, stream>>>(counts, row_ptr, cursor);
    scatter_kernel<<<eb, 256, 0, stream>>>(ei, cursor, col);

    encoder_kernel<<<(N_NODES + ENC_NPB - 1) / ENC_NPB, 256, 0, stream>>>(
        x, pos, enc_w, enc_b, Y, X);

    const int ab = (N_NODES * 64 + 255) / 256;   // one wave per node
    const int lb = (N_NODES + LIN_NPB - 1) / LIN_NPB;
    for (int layer = 0; layer < 3; ++layer) {
        lin_kernel<<<lb, 256, 0, stream>>>(X, lin_w, att_src, att_dst, h, a_src, a_dst);
        fused_gat_kernel<<<ab, 256, 0, stream>>>(row_ptr, col, a_src, a_dst, h,
                                                 conv_b, res_w, res_b, Y, X);
    }

    decoder_partial_kernel<<<DEC_BLOCKS, 256, 0, stream>>>(X, dec_w, dec_b, batch, partials);
    decoder_reduce_kernel<<<1, 256, 0, stream>>>(partials, out);
}

// Round 8
// 885.526 us; speedup vs baseline: 3.9228x; 1.0744x over previous
//
#include <hip/hip_runtime.h>
#include <hip/hip_bf16.h>

#define N_NODES  50000
#define N_EDGES  800000
#define E_TOT    850000   // edges + self loops
#define N_GRAPHS 64
#define NHID     64
#define NHEADS   4
#define HW       256      // NHEADS*NHID
#define NEG_SLOPE 0.2f
#define DEC_BLOCKS 512
#define LIN_NPB  16
#define ENC_NPB  32

__device__ __forceinline__ float bf2f(unsigned short u) {
    return __uint_as_float(((unsigned)u) << 16);
}
__device__ __forceinline__ float lrelu(float v) {
    return (v > 0.f) ? v : NEG_SLOPE * v;
}

// ---------------- encoder: Y = X = [x|pos] @ enc_w + enc_b (32 nodes/block) ----------------
__global__ __launch_bounds__(256) void encoder_kernel(
        const float* __restrict__ x, const float* __restrict__ pos,
        const float* __restrict__ enc_w, const float* __restrict__ enc_b,
        float* __restrict__ Y, float* __restrict__ X) {
    __shared__ float ws[128 * 64];       // 32 KB: whole enc_w
    __shared__ float xs[ENC_NPB][128];   // 16 KB: staged input rows
    int t = threadIdx.x;
    int base = blockIdx.x * ENC_NPB;
    int nx = min(ENC_NPB, N_NODES - base);
    for (int i = t; i < 128 * 64; i += 256) ws[i] = enc_w[i];
    for (int i = t; i < nx * 125; i += 256) {        // x rows are contiguous: coalesced
        int nn = i / 125, k = i - nn * 125;
        xs[nn][k] = x[(size_t)base * 125 + i];
    }
    for (int i = t; i < nx * 3; i += 256) {
        int nn = i / 3, k = i - nn * 3;
        xs[nn][125 + k] = pos[(size_t)(base + nn) * 3 + k];
    }
    __syncthreads();
    int c = t & 63, wv = t >> 6;
    float bias = enc_b[c];
    for (int nn = wv; nn < nx; nn += 4) {
        float acc = bias;
        #pragma unroll 16
        for (int k = 0; k < 128; ++k) acc += xs[nn][k] * ws[k * 64 + c];
        int n = base + nn;
        Y[n * 64 + c] = acc;
        X[n * 64 + c] = acc;
    }
}

// ---------------- CSR build ----------------
__global__ void hist_kernel(const int* __restrict__ ei, int* __restrict__ counts) {
    int e = blockIdx.x * blockDim.x + threadIdx.x;
    if (e >= E_TOT) return;
    int d = (e < N_EDGES) ? ei[N_EDGES + e] : (e - N_EDGES);
    atomicAdd(&counts[d], 1);
}

__global__ void scan_kernel(const int* __restrict__ counts, int* __restrict__ row_ptr,
                            int* __restrict__ cursor) {
    __shared__ int part[1024];
    int t = threadIdx.x;
    const int chunk = (N_NODES + 1023) / 1024;   // 49
    int base = t * chunk;
    int sum = 0;
    for (int i = 0; i < chunk; ++i) {
        int idx = base + i;
        if (idx < N_NODES) sum += counts[idx];
    }
    part[t] = sum;
    __syncthreads();
    for (int off = 1; off < 1024; off <<= 1) {
        int v = (t >= off) ? part[t - off] : 0;
        __syncthreads();
        part[t] += v;
        __syncthreads();
    }
    int run = (t == 0) ? 0 : part[t - 1];
    for (int i = 0; i < chunk; ++i) {
        int idx = base + i;
        if (idx < N_NODES) { row_ptr[idx] = run; cursor[idx] = run; run += counts[idx]; }
    }
    if (t == 1023) row_ptr[N_NODES] = part[1023];
}

__global__ void scatter_kernel(const int* __restrict__ ei, int* __restrict__ cursor,
                               int* __restrict__ col) {
    int e = blockIdx.x * blockDim.x + threadIdx.x;
    if (e >= E_TOT) return;
    int s, d;
    if (e < N_EDGES) { s = ei[e]; d = ei[N_EDGES + e]; }
    else             { s = d = e - N_EDGES; }
    int pos = atomicAdd(&cursor[d], 1);
    col[pos] = s;
}

// --- h = X @ lin_w (bf16), logits, AND res = X @ res_w + res_b (fp32); 16 nodes/block ---
__global__ __launch_bounds__(256) void lin_kernel(
        const float* __restrict__ X, const float* __restrict__ lin_w,
        const float* __restrict__ res_w, const float* __restrict__ res_b,
        const float* __restrict__ att_src, const float* __restrict__ att_dst,
        __hip_bfloat16* __restrict__ h, float* __restrict__ a_src,
        float* __restrict__ a_dst, float* __restrict__ res) {
    int t = threadIdx.x;            // 0..255; flat output channel
    int head = t >> 6, c = t & 63;
    int base = blockIdx.x * LIN_NPB;
    int nx = min(LIN_NPB, N_NODES - base);
    float wcol[64];                 // this thread's weight column (reused for both GEMMs)
    #pragma unroll
    for (int k = 0; k < 64; ++k) wcol[k] = lin_w[k * 256 + t];
    __shared__ float xs[LIN_NPB][64];
    for (int i = t; i < nx * 64; i += 256)
        xs[i >> 6][i & 63] = X[(size_t)base * 64 + i];
    __syncthreads();
    float asv = att_src[head * 64 + c];
    float adv = att_dst[head * 64 + c];
    for (int nn = 0; nn < nx; ++nn) {
        float acc = 0.f;
        #pragma unroll
        for (int k = 0; k < 64; ++k) acc += xs[nn][k] * wcol[k];
        int n = base + nn;
        h[n * 256 + t] = __float2bfloat16(acc);   // logits use fp32 acc (pre-rounding)
        float ps = acc * asv;
        float pd = acc * adv;
        #pragma unroll
        for (int off = 32; off >= 1; off >>= 1) {
            ps += __shfl_down(ps, off);
            pd += __shfl_down(pd, off);
        }
        if (c == 0) { a_src[n * 4 + head] = ps; a_dst[n * 4 + head] = pd; }
    }
    // ---- phase 2: residual GEMV with res_w column in the same registers ----
    float rb = res_b[t];
    #pragma unroll
    for (int k = 0; k < 64; ++k) wcol[k] = res_w[k * 256 + t];
    for (int nn = 0; nn < nx; ++nn) {
        float acc = rb;
        #pragma unroll
        for (int k = 0; k < 64; ++k) acc += xs[nn][k] * wcol[k];
        res[(size_t)(base + nn) * 256 + t] = acc;
    }
}

// ---- FUSED: attention softmax + gather + (precomputed res) + elu + head-mix + update ----
// one wave per dst node; lane owns 4 output channels (all in head = lane>>4)
__global__ void fused_gat_kernel(const int* __restrict__ rp, const int* __restrict__ col,
                                 const float* __restrict__ a_src, const float* __restrict__ a_dst,
                                 const __hip_bfloat16* __restrict__ h,
                                 const float* __restrict__ conv_b,
                                 const float* __restrict__ res,
                                 float* __restrict__ Y, float* __restrict__ X) {
    int n = (blockIdx.x * blockDim.x + threadIdx.x) >> 6;
    if (n >= N_NODES) return;
    int lane = threadIdx.x & 63;
    int head = lane >> 4;
    int base = rp[n];
    int deg  = rp[n + 1] - base;
    const ushort* hp = (const ushort*)h;
    float4 ad = ((const float4*)a_dst)[n];

    float a0 = 0.f, a1 = 0.f, a2 = 0.f, a3 = 0.f;

    if (deg <= 64) {
        int s = 0;
        float l0 = -3.0e38f, l1 = -3.0e38f, l2 = -3.0e38f, l3 = -3.0e38f;
        if (lane < deg) {
            s = col[base + lane];                       // coalesced
            float4 as = ((const float4*)a_src)[s];      // one 16B gather per edge
            l0 = lrelu(as.x + ad.x); l1 = lrelu(as.y + ad.y);
            l2 = lrelu(as.z + ad.z); l3 = lrelu(as.w + ad.w);
        }
        float m0 = l0, m1 = l1, m2 = l2, m3 = l3;
        #pragma unroll
        for (int off = 1; off < 64; off <<= 1) {
            m0 = fmaxf(m0, __shfl_xor(m0, off)); m1 = fmaxf(m1, __shfl_xor(m1, off));
            m2 = fmaxf(m2, __shfl_xor(m2, off)); m3 = fmaxf(m3, __shfl_xor(m3, off));
        }
        float e0 = (lane < deg) ? __expf(l0 - m0) : 0.f;
        float e1 = (lane < deg) ? __expf(l1 - m1) : 0.f;
        float e2 = (lane < deg) ? __expf(l2 - m2) : 0.f;
        float e3 = (lane < deg) ? __expf(l3 - m3) : 0.f;
        float z0 = e0, z1 = e1, z2 = e2, z3 = e3;
        #pragma unroll
        for (int off = 1; off < 64; off <<= 1) {
            z0 += __shfl_xor(z0, off); z1 += __shfl_xor(z1, off);
            z2 += __shfl_xor(z2, off); z3 += __shfl_xor(z3, off);
        }
        e0 /= z0; e1 /= z1; e2 /= z2; e3 /= z3;

        for (int j = 0; j < deg; ++j) {
            int   sj = __shfl(s, j);
            float w0 = __shfl(e0, j), w1 = __shfl(e1, j);
            float w2 = __shfl(e2, j), w3 = __shfl(e3, j);
            float w  = (head == 0) ? w0 : (head == 1) ? w1 : (head == 2) ? w2 : w3;
            ushort4 v = *(const ushort4*)(hp + (size_t)sj * 256 + lane * 4);
            a0 += w * bf2f(v.x); a1 += w * bf2f(v.y);
            a2 += w * bf2f(v.z); a3 += w * bf2f(v.w);
        }
    } else {
        float m0 = -3.0e38f, m1 = -3.0e38f, m2 = -3.0e38f, m3 = -3.0e38f;
        float z0 = 0.f, z1 = 0.f, z2 = 0.f, z3 = 0.f;
        for (int c0 = 0; c0 < deg; c0 += 64) {
            int j = c0 + lane;
            float l0 = -3.0e38f, l1 = -3.0e38f, l2 = -3.0e38f, l3 = -3.0e38f;
            if (j < deg) {
                int s = col[base + j];
                float4 as = ((const float4*)a_src)[s];
                l0 = lrelu(as.x + ad.x); l1 = lrelu(as.y + ad.y);
                l2 = lrelu(as.z + ad.z); l3 = lrelu(as.w + ad.w);
            }
            float c0m = l0, c1m = l1, c2m = l2, c3m = l3;
            #pragma unroll
            for (int off = 1; off < 64; off <<= 1) {
                c0m = fmaxf(c0m, __shfl_xor(c0m, off)); c1m = fmaxf(c1m, __shfl_xor(c1m, off));
                c2m = fmaxf(c2m, __shfl_xor(c2m, off)); c3m = fmaxf(c3m, __shfl_xor(c3m, off));
            }
            float n0 = fmaxf(m0, c0m), n1 = fmaxf(m1, c1m);
            float n2 = fmaxf(m2, c2m), n3 = fmaxf(m3, c3m);
            z0 *= __expf(m0 - n0); z1 *= __expf(m1 - n1);
            z2 *= __expf(m2 - n2); z3 *= __expf(m3 - n3);
            m0 = n0; m1 = n1; m2 = n2; m3 = n3;
            float e0 = (j < deg) ? __expf(l0 - m0) : 0.f;
            float e1 = (j < deg) ? __expf(l1 - m1) : 0.f;
            float e2 = (j < deg) ? __expf(l2 - m2) : 0.f;
            float e3 = (j < deg) ? __expf(l3 - m3) : 0.f;
            #pragma unroll
            for (int off = 1; off < 64; off <<= 1) {
                e0 += __shfl_xor(e0, off); e1 += __shfl_xor(e1, off);
                e2 += __shfl_xor(e2, off); e3 += __shfl_xor(e3, off);
            }
            z0 += e0; z1 += e1; z2 += e2; z3 += e3;
        }
        for (int c0 = 0; c0 < deg; c0 += 64) {
            int j = c0 + lane;
            int s = 0;
            float e0 = 0.f, e1 = 0.f, e2 = 0.f, e3 = 0.f;
            if (j < deg) {
                s = col[base + j];
                float4 as = ((const float4*)a_src)[s];
                e0 = __expf(lrelu(as.x + ad.x) - m0) / z0;
                e1 = __expf(lrelu(as.y + ad.y) - m1) / z1;
                e2 = __expf(lrelu(as.z + ad.z) - m2) / z2;
                e3 = __expf(lrelu(as.w + ad.w) - m3) / z3;
            }
            int cnt = min(64, deg - c0);
            for (int jj = 0; jj < cnt; ++jj) {
                int   sj = __shfl(s, jj);
                float w0 = __shfl(e0, jj), w1 = __shfl(e1, jj);
                float w2 = __shfl(e2, jj), w3 = __shfl(e3, jj);
                float w  = (head == 0) ? w0 : (head == 1) ? w1 : (head == 2) ? w2 : w3;
                ushort4 v = *(const ushort4*)(hp + (size_t)sj * 256 + lane * 4);
                a0 += w * bf2f(v.x); a1 += w * bf2f(v.y);
                a2 += w * bf2f(v.z); a3 += w * bf2f(v.w);
            }
        }
    }

    // ---- add precomputed residual, elu, lane-local head-mix, update ----
    float4 rr = ((const float4*)res)[(size_t)n * 64 + lane];   // coalesced 16B/lane
    float4 cb = ((const float4*)conv_b)[lane];
    float v0 = a0 + cb.x + rr.x, v1 = a1 + cb.y + rr.y;
    float v2 = a2 + cb.z + rr.z, v3 = a3 + cb.w + rr.w;
    v0 = (v0 > 0.f) ? v0 : (__expf(v0) - 1.f);
    v1 = (v1 > 0.f) ? v1 : (__expf(v1) - 1.f);
    v2 = (v2 > 0.f) ? v2 : (__expf(v2) - 1.f);
    v3 = (v3 > 0.f) ? v3 : (__expf(v3) - 1.f);
    float mixed = 0.25f * (v0 + v1 + v2 + v3);

    float xv = X[n * 64 + lane];
    float y = Y[n * 64 + lane];
    y  = y + (mixed - y - xv);    // DT=ALPHA=GAMMA=1
    xv = xv + y;
    Y[n * 64 + lane] = y;
    X[n * 64 + lane] = xv;
}

// ---------------- decoder: per-block partials (no global atomics) ----------------
__global__ void decoder_partial_kernel(const float* __restrict__ X, const float* __restrict__ dec_w,
                                       const float* __restrict__ dec_b, const int* __restrict__ batch,
                                       float* __restrict__ partials) {
    __shared__ float sg[N_GRAPHS];
    int t = threadIdx.x;                      // 256 threads = 4 waves
    if (t < N_GRAPHS) sg[t] = 0.f;
    __syncthreads();
    int lane = t & 63;
    int wave = t >> 6;
    const int npb = (N_NODES + DEC_BLOCKS - 1) / DEC_BLOCKS;   // 98
    int start = blockIdx.x * npb;
    int end   = min(start + npb, N_NODES);
    float dw = dec_w[lane];
    float db = dec_b[0];
    for (int n = start + wave; n < end; n += 4) {
        float p = X[n * 64 + lane] * dw;
        #pragma unroll
        for (int off = 32; off >= 1; off >>= 1) p += __shfl_down(p, off);
        if (lane == 0) atomicAdd(&sg[batch[n]], p + db);
    }
    __syncthreads();
    if (t < N_GRAPHS) partials[blockIdx.x * N_GRAPHS + t] = sg[t];
}

__global__ void decoder_reduce_kernel(const float* __restrict__ partials, float* __restrict__ out) {
    __shared__ float red[256];
    int t = threadIdx.x;
    int g = t & 63, j = t >> 6;
    float s = 0.f;
    for (int b = j * (DEC_BLOCKS / 4); b < (j + 1) * (DEC_BLOCKS / 4); ++b)
        s += partials[b * N_GRAPHS + g];
    red[t] = s;
    __syncthreads();
    if (t < 64) out[g] = red[g] + red[64 + g] + red[128 + g] + red[192 + g];
}

extern "C" void kernel_launch(void* const* d_in, const int* in_sizes, int n_in,
                              void* d_out, int out_size, void* d_ws, size_t ws_size,
                              hipStream_t stream) {
    const float* x       = (const float*)d_in[0];
    const float* pos     = (const float*)d_in[1];
    const int*   ei      = (const int*)d_in[2];
    const int*   batch   = (const int*)d_in[3];
    const float* enc_w   = (const float*)d_in[4];
    const float* enc_b   = (const float*)d_in[5];
    const float* res_w   = (const float*)d_in[6];
    const float* res_b   = (const float*)d_in[7];
    const float* lin_w   = (const float*)d_in[8];
    const float* att_src = (const float*)d_in[9];
    const float* att_dst = (const float*)d_in[10];
    const float* conv_b  = (const float*)d_in[11];
    const float* dec_w   = (const float*)d_in[12];
    const float* dec_b   = (const float*)d_in[13];
    float* out = (float*)d_out;

    char* ws = (char*)d_ws;
    size_t off = 0;
    auto alloc = [&](size_t bytes) -> void* {
        void* p = ws + off;
        off += (bytes + 255) & ~size_t(255);
        return p;
    };
    float* Y       = (float*)alloc((size_t)N_NODES * 64 * sizeof(float));
    float* X       = (float*)alloc((size_t)N_NODES * 64 * sizeof(float));
    __hip_bfloat16* h = (__hip_bfloat16*)alloc((size_t)N_NODES * HW * sizeof(__hip_bfloat16));
    float* res     = (float*)alloc((size_t)N_NODES * HW * sizeof(float));
    float* a_src   = (float*)alloc((size_t)N_NODES * NHEADS * sizeof(float));
    float* a_dst   = (float*)alloc((size_t)N_NODES * NHEADS * sizeof(float));
    float* partials= (float*)alloc((size_t)DEC_BLOCKS * N_GRAPHS * sizeof(float));
    int*   counts  = (int*)alloc((size_t)N_NODES * sizeof(int));
    int*   row_ptr = (int*)alloc((size_t)(N_NODES + 1) * sizeof(int));
    int*   cursor  = (int*)alloc((size_t)N_NODES * sizeof(int));
    int*   col     = (int*)alloc((size_t)E_TOT * sizeof(int));

    // ---- CSR build (dst is static; built each call for determinism) ----
    hipMemsetAsync(counts, 0, (size_t)N_NODES * sizeof(int), stream);
    const int eb = (E_TOT + 255) / 256;
    hist_kernel<<<eb, 256, 0, stream>>>(ei, counts);
    scan_kernel<<<1, 1024, 0, stream>>>(counts, row_ptr, cursor);
    scatter_kernel<<<eb, 256, 0, stream>>>(ei, cursor, col);

    encoder_kernel<<<(N_NODES + ENC_NPB - 1) / ENC_NPB, 256, 0, stream>>>(
        x, pos, enc_w, enc_b, Y, X);

    const int ab = (N_NODES * 64 + 255) / 256;   // one wave per node
    const int lb = (N_NODES + LIN_NPB - 1) / LIN_NPB;
    for (int layer = 0; layer < 3; ++layer) {
        lin_kernel<<<lb, 256, 0, stream>>>(X, lin_w, res_w, res_b, att_src, att_dst,
                                           h, a_src, a_dst, res);
        fused_gat_kernel<<<ab, 256, 0, stream>>>(row_ptr, col, a_src, a_dst, h,
                                                 conv_b, res, Y, X);
    }

    decoder_partial_kernel<<<DEC_BLOCKS, 256, 0, stream>>>(X, dec_w, dec_b, batch, partials);
    decoder_reduce_kernel<<<1, 256, 0, stream>>>(partials, out);
}

// Round 9
// 769.160 us; speedup vs baseline: 4.5163x; 1.1513x over previous
//
#include <hip/hip_runtime.h>
#include <hip/hip_bf16.h>

#define N_NODES  50000
#define N_EDGES  800000
#define E_TOT    850000   // edges + self loops
#define N_GRAPHS 64
#define NHID     64
#define NHEADS   4
#define HW       256      // NHEADS*NHID
#define NEG_SLOPE 0.2f
#define DEC_BLOCKS 512
#define LIN_NPB  16
#define ENC_NPB  32
#define SCAN_NB  ((N_NODES + 255) / 256)   // 196

__device__ __forceinline__ float bf2f(unsigned short u) {
    return __uint_as_float(((unsigned)u) << 16);
}
__device__ __forceinline__ float lrelu(float v) {
    return (v > 0.f) ? v : NEG_SLOPE * v;
}

// ---------------- encoder: Y = X = [x|pos] @ enc_w + enc_b (32 nodes/block) ----------------
__global__ __launch_bounds__(256) void encoder_kernel(
        const float* __restrict__ x, const float* __restrict__ pos,
        const float* __restrict__ enc_w, const float* __restrict__ enc_b,
        float* __restrict__ Y, float* __restrict__ X) {
    __shared__ float ws[128 * 64];       // 32 KB: whole enc_w
    __shared__ float xs[ENC_NPB][128];   // 16 KB: staged input rows
    int t = threadIdx.x;
    int base = blockIdx.x * ENC_NPB;
    int nx = min(ENC_NPB, N_NODES - base);
    for (int i = t; i < 128 * 64; i += 256) ws[i] = enc_w[i];
    for (int i = t; i < nx * 125; i += 256) {        // x rows are contiguous: coalesced
        int nn = i / 125, k = i - nn * 125;
        xs[nn][k] = x[(size_t)base * 125 + i];
    }
    for (int i = t; i < nx * 3; i += 256) {
        int nn = i / 3, k = i - nn * 3;
        xs[nn][125 + k] = pos[(size_t)(base + nn) * 3 + k];
    }
    __syncthreads();
    int c = t & 63, wv = t >> 6;
    float bias = enc_b[c];
    for (int nn = wv; nn < nx; nn += 4) {
        float acc = bias;
        #pragma unroll 16
        for (int k = 0; k < 128; ++k) acc += xs[nn][k] * ws[k * 64 + c];
        int n = base + nn;
        Y[n * 64 + c] = acc;
        X[n * 64 + c] = acc;
    }
}

// ---------------- CSR build ----------------
__global__ void hist_kernel(const int* __restrict__ ei, int* __restrict__ counts) {
    int e = blockIdx.x * blockDim.x + threadIdx.x;
    if (e >= E_TOT) return;
    int d = (e < N_EDGES) ? ei[N_EDGES + e] : (e - N_EDGES);
    atomicAdd(&counts[d], 1);
}

// phase A: per-block sums of counts
__global__ __launch_bounds__(256) void scan_reduce_kernel(const int* __restrict__ counts,
                                                          int* __restrict__ bsum) {
    __shared__ int s[256];
    int t = threadIdx.x;
    int i = blockIdx.x * 256 + t;
    s[t] = (i < N_NODES) ? counts[i] : 0;
    __syncthreads();
    #pragma unroll
    for (int off = 128; off >= 1; off >>= 1) {
        if (t < off) s[t] += s[t + off];
        __syncthreads();
    }
    if (t == 0) bsum[blockIdx.x] = s[0];
}

// phase B: exclusive scan of the 196 block sums (single small block)
__global__ __launch_bounds__(256) void scan_bsum_kernel(const int* __restrict__ bsum,
                                                        int* __restrict__ boff) {
    __shared__ int a[256];
    int t = threadIdx.x;
    int v = (t < SCAN_NB) ? bsum[t] : 0;
    a[t] = v;
    __syncthreads();
    #pragma unroll
    for (int off = 1; off < 256; off <<= 1) {
        int u = (t >= off) ? a[t - off] : 0;
        __syncthreads();
        a[t] += u;
        __syncthreads();
    }
    if (t < SCAN_NB) boff[t] = a[t] - v;   // exclusive
}

// phase C: in-block scan of chunk + block offset -> row_ptr, cursor
__global__ __launch_bounds__(256) void scan_write_kernel(const int* __restrict__ counts,
                                                         const int* __restrict__ boff,
                                                         int* __restrict__ row_ptr,
                                                         int* __restrict__ cursor) {
    __shared__ int a[256];
    int t = threadIdx.x;
    int i = blockIdx.x * 256 + t;
    int v = (i < N_NODES) ? counts[i] : 0;
    a[t] = v;
    __syncthreads();
    #pragma unroll
    for (int off = 1; off < 256; off <<= 1) {
        int u = (t >= off) ? a[t - off] : 0;
        __syncthreads();
        a[t] += u;
        __syncthreads();
    }
    if (i < N_NODES) {
        int ex = boff[blockIdx.x] + a[t] - v;
        row_ptr[i] = ex;
        cursor[i]  = ex;
        if (i == N_NODES - 1) row_ptr[N_NODES] = E_TOT;  // total is static
    }
}

__global__ void scatter_kernel(const int* __restrict__ ei, int* __restrict__ cursor,
                               int* __restrict__ col) {
    int e = blockIdx.x * blockDim.x + threadIdx.x;
    if (e >= E_TOT) return;
    int s, d;
    if (e < N_EDGES) { s = ei[e]; d = ei[N_EDGES + e]; }
    else             { s = d = e - N_EDGES; }
    int pos = atomicAdd(&cursor[d], 1);
    col[pos] = s;
}

// --- h = X @ lin_w (bf16), logits, AND res = X @ res_w + res_b (fp32); 16 nodes/block ---
__global__ __launch_bounds__(256) void lin_kernel(
        const float* __restrict__ X, const float* __restrict__ lin_w,
        const float* __restrict__ res_w, const float* __restrict__ res_b,
        const float* __restrict__ att_src, const float* __restrict__ att_dst,
        __hip_bfloat16* __restrict__ h, float* __restrict__ a_src,
        float* __restrict__ a_dst, float* __restrict__ res) {
    int t = threadIdx.x;            // 0..255; flat output channel
    int head = t >> 6, c = t & 63;
    int base = blockIdx.x * LIN_NPB;
    int nx = min(LIN_NPB, N_NODES - base);
    float wcol[64];                 // this thread's weight column (reused for both GEMMs)
    #pragma unroll
    for (int k = 0; k < 64; ++k) wcol[k] = lin_w[k * 256 + t];
    __shared__ float xs[LIN_NPB][64];
    for (int i = t; i < nx * 64; i += 256)
        xs[i >> 6][i & 63] = X[(size_t)base * 64 + i];
    __syncthreads();
    float asv = att_src[head * 64 + c];
    float adv = att_dst[head * 64 + c];
    for (int nn = 0; nn < nx; ++nn) {
        float acc = 0.f;
        #pragma unroll
        for (int k = 0; k < 64; ++k) acc += xs[nn][k] * wcol[k];
        int n = base + nn;
        h[n * 256 + t] = __float2bfloat16(acc);   // logits use fp32 acc (pre-rounding)
        float ps = acc * asv;
        float pd = acc * adv;
        #pragma unroll
        for (int off = 32; off >= 1; off >>= 1) {
            ps += __shfl_down(ps, off);
            pd += __shfl_down(pd, off);
        }
        if (c == 0) { a_src[n * 4 + head] = ps; a_dst[n * 4 + head] = pd; }
    }
    // ---- phase 2: residual GEMV with res_w column in the same registers ----
    float rb = res_b[t];
    #pragma unroll
    for (int k = 0; k < 64; ++k) wcol[k] = res_w[k * 256 + t];
    for (int nn = 0; nn < nx; ++nn) {
        float acc = rb;
        #pragma unroll
        for (int k = 0; k < 64; ++k) acc += xs[nn][k] * wcol[k];
        res[(size_t)(base + nn) * 256 + t] = acc;
    }
}

// ---- FUSED: attention softmax + gather + (precomputed res) + elu + head-mix + update ----
// one wave per dst node; lane owns 4 output channels (all in head = lane>>4)
__global__ void fused_gat_kernel(const int* __restrict__ rp, const int* __restrict__ col,
                                 const float* __restrict__ a_src, const float* __restrict__ a_dst,
                                 const __hip_bfloat16* __restrict__ h,
                                 const float* __restrict__ conv_b,
                                 const float* __restrict__ res,
                                 float* __restrict__ Y, float* __restrict__ X) {
    int n = (blockIdx.x * blockDim.x + threadIdx.x) >> 6;
    if (n >= N_NODES) return;
    int lane = threadIdx.x & 63;
    int head = lane >> 4;
    int base = rp[n];
    int deg  = rp[n + 1] - base;
    const ushort* hp = (const ushort*)h;
    float4 ad = ((const float4*)a_dst)[n];

    float a0 = 0.f, a1 = 0.f, a2 = 0.f, a3 = 0.f;

    if (deg <= 64) {
        int s = 0;
        float l0 = -3.0e38f, l1 = -3.0e38f, l2 = -3.0e38f, l3 = -3.0e38f;
        if (lane < deg) {
            s = col[base + lane];                       // coalesced
            float4 as = ((const float4*)a_src)[s];      // one 16B gather per edge
            l0 = lrelu(as.x + ad.x); l1 = lrelu(as.y + ad.y);
            l2 = lrelu(as.z + ad.z); l3 = lrelu(as.w + ad.w);
        }
        float m0 = l0, m1 = l1, m2 = l2, m3 = l3;
        #pragma unroll
        for (int off = 1; off < 64; off <<= 1) {
            m0 = fmaxf(m0, __shfl_xor(m0, off)); m1 = fmaxf(m1, __shfl_xor(m1, off));
            m2 = fmaxf(m2, __shfl_xor(m2, off)); m3 = fmaxf(m3, __shfl_xor(m3, off));
        }
        float e0 = (lane < deg) ? __expf(l0 - m0) : 0.f;
        float e1 = (lane < deg) ? __expf(l1 - m1) : 0.f;
        float e2 = (lane < deg) ? __expf(l2 - m2) : 0.f;
        float e3 = (lane < deg) ? __expf(l3 - m3) : 0.f;
        float z0 = e0, z1 = e1, z2 = e2, z3 = e3;
        #pragma unroll
        for (int off = 1; off < 64; off <<= 1) {
            z0 += __shfl_xor(z0, off); z1 += __shfl_xor(z1, off);
            z2 += __shfl_xor(z2, off); z3 += __shfl_xor(z3, off);
        }
        e0 /= z0; e1 /= z1; e2 /= z2; e3 /= z3;

        for (int j = 0; j < deg; ++j) {
            int   sj = __shfl(s, j);
            float w0 = __shfl(e0, j), w1 = __shfl(e1, j);
            float w2 = __shfl(e2, j), w3 = __shfl(e3, j);
            float w  = (head == 0) ? w0 : (head == 1) ? w1 : (head == 2) ? w2 : w3;
            ushort4 v = *(const ushort4*)(hp + (size_t)sj * 256 + lane * 4);
            a0 += w * bf2f(v.x); a1 += w * bf2f(v.y);
            a2 += w * bf2f(v.z); a3 += w * bf2f(v.w);
        }
    } else {
        float m0 = -3.0e38f, m1 = -3.0e38f, m2 = -3.0e38f, m3 = -3.0e38f;
        float z0 = 0.f, z1 = 0.f, z2 = 0.f, z3 = 0.f;
        for (int c0 = 0; c0 < deg; c0 += 64) {
            int j = c0 + lane;
            float l0 = -3.0e38f, l1 = -3.0e38f, l2 = -3.0e38f, l3 = -3.0e38f;
            if (j < deg) {
                int s = col[base + j];
                float4 as = ((const float4*)a_src)[s];
                l0 = lrelu(as.x + ad.x); l1 = lrelu(as.y + ad.y);
                l2 = lrelu(as.z + ad.z); l3 = lrelu(as.w + ad.w);
            }
            float c0m = l0, c1m = l1, c2m = l2, c3m = l3;
            #pragma unroll
            for (int off = 1; off < 64; off <<= 1) {
                c0m = fmaxf(c0m, __shfl_xor(c0m, off)); c1m = fmaxf(c1m, __shfl_xor(c1m, off));
                c2m = fmaxf(c2m, __shfl_xor(c2m, off)); c3m = fmaxf(c3m, __shfl_xor(c3m, off));
            }
            float n0 = fmaxf(m0, c0m), n1 = fmaxf(m1, c1m);
            float n2 = fmaxf(m2, c2m), n3 = fmaxf(m3, c3m);
            z0 *= __expf(m0 - n0); z1 *= __expf(m1 - n1);
            z2 *= __expf(m2 - n2); z3 *= __expf(m3 - n3);
            m0 = n0; m1 = n1; m2 = n2; m3 = n3;
            float e0 = (j < deg) ? __expf(l0 - m0) : 0.f;
            float e1 = (j < deg) ? __expf(l1 - m1) : 0.f;
            float e2 = (j < deg) ? __expf(l2 - m2) : 0.f;
            float e3 = (j < deg) ? __expf(l3 - m3) : 0.f;
            #pragma unroll
            for (int off = 1; off < 64; off <<= 1) {
                e0 += __shfl_xor(e0, off); e1 += __shfl_xor(e1, off);
                e2 += __shfl_xor(e2, off); e3 += __shfl_xor(e3, off);
            }
            z0 += e0; z1 += e1; z2 += e2; z3 += e3;
        }
        for (int c0 = 0; c0 < deg; c0 += 64) {
            int j = c0 + lane;
            int s = 0;
            float e0 = 0.f, e1 = 0.f, e2 = 0.f, e3 = 0.f;
            if (j < deg) {
                s = col[base + j];
                float4 as = ((const float4*)a_src)[s];
                e0 = __expf(lrelu(as.x + ad.x) - m0) / z0;
                e1 = __expf(lrelu(as.y + ad.y) - m1) / z1;
                e2 = __expf(lrelu(as.z + ad.z) - m2) / z2;
                e3 = __expf(lrelu(as.w + ad.w) - m3) / z3;
            }
            int cnt = min(64, deg - c0);
            for (int jj = 0; jj < cnt; ++jj) {
                int   sj = __shfl(s, jj);
                float w0 = __shfl(e0, jj), w1 = __shfl(e1, jj);
                float w2 = __shfl(e2, jj), w3 = __shfl(e3, jj);
                float w  = (head == 0) ? w0 : (head == 1) ? w1 : (head == 2) ? w2 : w3;
                ushort4 v = *(const ushort4*)(hp + (size_t)sj * 256 + lane * 4);
                a0 += w * bf2f(v.x); a1 += w * bf2f(v.y);
                a2 += w * bf2f(v.z); a3 += w * bf2f(v.w);
            }
        }
    }

    // ---- add precomputed residual, elu, lane-local head-mix, update ----
    float4 rr = ((const float4*)res)[(size_t)n * 64 + lane];   // coalesced 16B/lane
    float4 cb = ((const float4*)conv_b)[lane];
    float v0 = a0 + cb.x + rr.x, v1 = a1 + cb.y + rr.y;
    float v2 = a2 + cb.z + rr.z, v3 = a3 + cb.w + rr.w;
    v0 = (v0 > 0.f) ? v0 : (__expf(v0) - 1.f);
    v1 = (v1 > 0.f) ? v1 : (__expf(v1) - 1.f);
    v2 = (v2 > 0.f) ? v2 : (__expf(v2) - 1.f);
    v3 = (v3 > 0.f) ? v3 : (__expf(v3) - 1.f);
    float mixed = 0.25f * (v0 + v1 + v2 + v3);

    float xv = X[n * 64 + lane];
    float y = Y[n * 64 + lane];
    y  = y + (mixed - y - xv);    // DT=ALPHA=GAMMA=1
    xv = xv + y;
    Y[n * 64 + lane] = y;
    X[n * 64 + lane] = xv;
}

// ---------------- decoder: per-block partials (no global atomics) ----------------
__global__ void decoder_partial_kernel(const float* __restrict__ X, const float* __restrict__ dec_w,
                                       const float* __restrict__ dec_b, const int* __restrict__ batch,
                                       float* __restrict__ partials) {
    __shared__ float sg[N_GRAPHS];
    int t = threadIdx.x;                      // 256 threads = 4 waves
    if (t < N_GRAPHS) sg[t] = 0.f;
    __syncthreads();
    int lane = t & 63;
    int wave = t >> 6;
    const int npb = (N_NODES + DEC_BLOCKS - 1) / DEC_BLOCKS;   // 98
    int start = blockIdx.x * npb;
    int end   = min(start + npb, N_NODES);
    float dw = dec_w[lane];
    float db = dec_b[0];
    for (int n = start + wave; n < end; n += 4) {
        float p = X[n * 64 + lane] * dw;
        #pragma unroll
        for (int off = 32; off >= 1; off >>= 1) p += __shfl_down(p, off);
        if (lane == 0) atomicAdd(&sg[batch[n]], p + db);
    }
    __syncthreads();
    if (t < N_GRAPHS) partials[blockIdx.x * N_GRAPHS + t] = sg[t];
}

__global__ void decoder_reduce_kernel(const float* __restrict__ partials, float* __restrict__ out) {
    __shared__ float red[256];
    int t = threadIdx.x;
    int g = t & 63, j = t >> 6;
    float s = 0.f;
    for (int b = j * (DEC_BLOCKS / 4); b < (j + 1) * (DEC_BLOCKS / 4); ++b)
        s += partials[b * N_GRAPHS + g];
    red[t] = s;
    __syncthreads();
    if (t < 64) out[g] = red[g] + red[64 + g] + red[128 + g] + red[192 + g];
}

extern "C" void kernel_launch(void* const* d_in, const int* in_sizes, int n_in,
                              void* d_out, int out_size, void* d_ws, size_t ws_size,
                              hipStream_t stream) {
    const float* x       = (const float*)d_in[0];
    const float* pos     = (const float*)d_in[1];
    const int*   ei      = (const int*)d_in[2];
    const int*   batch   = (const int*)d_in[3];
    const float* enc_w   = (const float*)d_in[4];
    const float* enc_b   = (const float*)d_in[5];
    const float* res_w   = (const float*)d_in[6];
    const float* res_b   = (const float*)d_in[7];
    const float* lin_w   = (const float*)d_in[8];
    const float* att_src = (const float*)d_in[9];
    const float* att_dst = (const float*)d_in[10];
    const float* conv_b  = (const float*)d_in[11];
    const float* dec_w   = (const float*)d_in[12];
    const float* dec_b   = (const float*)d_in[13];
    float* out = (float*)d_out;

    char* ws = (char*)d_ws;
    size_t off = 0;
    auto alloc = [&](size_t bytes) -> void* {
        void* p = ws + off;
        off += (bytes + 255) & ~size_t(255);
        return p;
    };
    float* Y       = (float*)alloc((size_t)N_NODES * 64 * sizeof(float));
    float* X       = (float*)alloc((size_t)N_NODES * 64 * sizeof(float));
    __hip_bfloat16* h = (__hip_bfloat16*)alloc((size_t)N_NODES * HW * sizeof(__hip_bfloat16));
    float* res     = (float*)alloc((size_t)N_NODES * HW * sizeof(float));
    float* a_src   = (float*)alloc((size_t)N_NODES * NHEADS * sizeof(float));
    float* a_dst   = (float*)alloc((size_t)N_NODES * NHEADS * sizeof(float));
    float* partials= (float*)alloc((size_t)DEC_BLOCKS * N_GRAPHS * sizeof(float));
    int*   counts  = (int*)alloc((size_t)N_NODES * sizeof(int));
    int*   row_ptr = (int*)alloc((size_t)(N_NODES + 1) * sizeof(int));
    int*   cursor  = (int*)alloc((size_t)N_NODES * sizeof(int));
    int*   col     = (int*)alloc((size_t)E_TOT * sizeof(int));
    int*   bsum    = (int*)alloc((size_t)SCAN_NB * sizeof(int));
    int*   boff    = (int*)alloc((size_t)SCAN_NB * sizeof(int));

    // ---- CSR build (dst is static; built each call for determinism) ----
    hipMemsetAsync(counts, 0, (size_t)N_NODES * sizeof(int), stream);
    const int eb = (E_TOT + 255) / 256;
    hist_kernel<<<eb, 256, 0, stream>>>(ei, counts);
    scan_reduce_kernel<<<SCAN_NB, 256, 0, stream>>>(counts, bsum);
    scan_bsum_kernel<<<1, 256, 0, stream>>>(bsum, boff);
    scan_write_kernel<<<SCAN_NB, 256, 0, stream>>>(counts, boff, row_ptr, cursor);
    scatter_kernel<<<eb, 256, 0, stream>>>(ei, cursor, col);

    encoder_kernel<<<(N_NODES + ENC_NPB - 1) / ENC_NPB, 256, 0, stream>>>(
        x, pos, enc_w, enc_b, Y, X);

    const int ab = (N_NODES * 64 + 255) / 256;   // one wave per node
    const int lb = (N_NODES + LIN_NPB - 1) / LIN_NPB;
    for (int layer = 0; layer < 3; ++layer) {
        lin_kernel<<<lb, 256, 0, stream>>>(X, lin_w, res_w, res_b, att_src, att_dst,
                                           h, a_src, a_dst, res);
        fused_gat_kernel<<<ab, 256, 0, stream>>>(row_ptr, col, a_src, a_dst, h,
                                                 conv_b, res, Y, X);
    }

    decoder_partial_kernel<<<DEC_BLOCKS, 256, 0, stream>>>(X, dec_w, dec_b, batch, partials);
    decoder_reduce_kernel<<<1, 256, 0, stream>>>(partials, out);
}